// Round 5
// baseline (16191.089 us; speedup 1.0000x reference)
//
#include <hip/hip_runtime.h>
#include <hip/hip_bf16.h>

// Model constants
#define B_ 64
#define IMG_ 224
#define P_ 16
#define G_ 14
#define NP_ 196
#define N_ 197
#define DIM_ 384
#define DEPTH_ 12
#define H_ 12
#define DH_ 32
#define INNER_ 384
#define MLP_ 1536
#define NCLS_ 1000
#define PD_ 1792
#define EPS_ 1e-5f

typedef __hip_bfloat16 bf16;

__device__ __forceinline__ float b2f(bf16 x) { return __bfloat162float(x); }
__device__ __forceinline__ bf16 f2b(float x) { return __float2bfloat16(x); }

// ---------------------------------------------------------------- mean image (bf16)
__global__ __launch_bounds__(256) void mean_kernel(const float* __restrict__ img,
                                                   bf16* __restrict__ meanimg) {
    int idx = blockIdx.x * 256 + threadIdx.x;
    if (idx >= B_ * 50176) return;
    int b = idx / 50176;
    int yx = idx - b * 50176;
    const float* p = img + (size_t)b * 3 * 50176 + yx;
    meanimg[idx] = f2b((p[0] + p[50176] + p[100352]) * (1.0f / 3.0f));
}

// ------------------------------------------------------------- patch matrix (chunk)
__global__ __launch_bounds__(256) void patches_kernel(const float* __restrict__ img,
                                                      const bf16* __restrict__ meanimg,
                                                      bf16* __restrict__ patches, int bp0) {
    int idx = blockIdx.x * 256 + threadIdx.x;
    if (idx >= 6272 * 256) return;
    int pix = idx & 255;
    int px = pix & 15, py = pix >> 4;
    int lbp = idx >> 8;
    int bp = bp0 + lbp;
    int p = bp % NP_;
    int b = bp / NP_;
    int gy = p / G_, gx = p - gy * G_;
    int y = gy * P_ + py, x = gx * P_ + px;
    const float* ib = img + (size_t)b * 3 * 50176 + y * 224 + x;
    bf16* out = patches + (size_t)lbp * PD_ + pix * 7;
    out[0] = f2b(ib[0]);
    out[1] = f2b(ib[50176]);
    out[2] = f2b(ib[100352]);
    const bf16* mb = meanimg + (size_t)b * 50176;
    out[3] = (x >= 8)  ? mb[y * 224 + x - 8]   : f2b(0.0f);   // l2
    out[4] = (x < 216) ? mb[y * 224 + x + 8]   : f2b(0.0f);   // r2
    out[5] = (y >= 8)  ? mb[(y - 8) * 224 + x] : f2b(0.0f);   // t2
    out[6] = (y < 216) ? mb[(y + 8) * 224 + x] : f2b(0.0f);   // b2
}

// --------------------------------------------------- cls + pos_emb assembly
__global__ __launch_bounds__(256) void addpos_kernel(const bf16* __restrict__ pe,
                                                     const float* __restrict__ cls_tok,
                                                     const float* __restrict__ pos_emb,
                                                     float* __restrict__ x) {
    int idx = blockIdx.x * 256 + threadIdx.x;
    if (idx >= B_ * N_ * DIM_) return;
    int c = idx % DIM_;
    int r = idx / DIM_;
    int t = r % N_;
    int b = r / N_;
    float v = (t == 0) ? cls_tok[c]
                       : b2f(pe[((size_t)(b * NP_ + t - 1)) * DIM_ + c]);
    x[idx] = v + pos_emb[t * DIM_ + c];
}

// ------------------------------------------------------------------ layernorm
__global__ __launch_bounds__(256) void ln_kernel(const float* __restrict__ in,
                                                 long in_stride,
                                                 const float* __restrict__ g,
                                                 const float* __restrict__ bb,
                                                 bf16* __restrict__ out, int rows) {
    int wave = threadIdx.x >> 6;
    int lane = threadIdx.x & 63;
    int row = blockIdx.x * 4 + wave;
    if (row >= rows) return;
    const float* p = in + (size_t)row * in_stride;
    float v[6];
    float s = 0.0f, s2 = 0.0f;
#pragma unroll
    for (int i = 0; i < 6; i++) {
        v[i] = p[lane + 64 * i];
        s += v[i];
        s2 += v[i] * v[i];
    }
#pragma unroll
    for (int m = 32; m >= 1; m >>= 1) {
        s += __shfl_xor(s, m);
        s2 += __shfl_xor(s2, m);
    }
    float mu = s * (1.0f / 384.0f);
    float var = s2 * (1.0f / 384.0f) - mu * mu;
    var = fmaxf(var, 0.0f);
    float inv = rsqrtf(var + EPS_);
    bf16* q = out + (size_t)row * DIM_;
#pragma unroll
    for (int i = 0; i < 6; i++) {
        int c = lane + 64 * i;
        q[c] = f2b((v[i] - mu) * inv * g[c] + bb[c]);
    }
}

// ------------------------------------------------------------------ GEMM
// C[M,N] = A[M,K] @ W[N,K]^T (+bias) (+res) (gelu).  MODE 0: bias. 1: bias+res. 2: bias+GELU.
template <int MODE, typename OutT>
__global__ __launch_bounds__(256) void gemm_kernel(const bf16* __restrict__ A,
                                                   const float* __restrict__ W,
                                                   const float* __restrict__ bias,
                                                   const float* res, OutT* C,
                                                   int M, int N, int K) {
    __shared__ float As[32][65];
    __shared__ float Ws[32][65];
    int tid = threadIdx.x;
    int rowBase = blockIdx.y * 64;
    int colBase = blockIdx.x * 64;
    int lr = tid >> 2;
    int lk = (tid & 3) * 8;
    int tx = tid & 15, ty = tid >> 4;
    float acc[4][4] = {};
    for (int k0 = 0; k0 < K; k0 += 32) {
        int gr = rowBase + lr;
        const bf16* asrc = A + (size_t)gr * K + k0 + lk;
        bool aok = (gr < M);
#pragma unroll
        for (int e = 0; e < 8; e++) As[lk + e][lr] = aok ? b2f(asrc[e]) : 0.0f;
        int gc = colBase + lr;
        const float* wsrc = W + (size_t)gc * K + k0 + lk;
        bool wok = (gc < N);
#pragma unroll
        for (int e = 0; e < 8; e++) Ws[lk + e][lr] = wok ? wsrc[e] : 0.0f;
        __syncthreads();
#pragma unroll
        for (int kk = 0; kk < 32; kk++) {
            float a[4], b[4];
#pragma unroll
            for (int i = 0; i < 4; i++) a[i] = As[kk][ty * 4 + i];
#pragma unroll
            for (int j = 0; j < 4; j++) b[j] = Ws[kk][tx * 4 + j];
#pragma unroll
            for (int i = 0; i < 4; i++)
#pragma unroll
                for (int j = 0; j < 4; j++) acc[i][j] += a[i] * b[j];
        }
        __syncthreads();
    }
#pragma unroll
    for (int i = 0; i < 4; i++) {
        int r = rowBase + ty * 4 + i;
        if (r >= M) continue;
#pragma unroll
        for (int j = 0; j < 4; j++) {
            int c = colBase + tx * 4 + j;
            if (c >= N) continue;
            float v = acc[i][j];
            if (bias) v += bias[c];
            if constexpr (MODE == 1) v += res[(size_t)r * N + c];
            if constexpr (MODE == 2) v = 0.5f * v * (1.0f + erff(v * 0.70710678118f));
            C[(size_t)r * N + c] = (OutT)v;
        }
    }
}

// ------------------------------------------------------------------ attention
__global__ __launch_bounds__(256) void attn_kernel(const bf16* __restrict__ qkv,
                                                   const float* __restrict__ scale,
                                                   bf16* __restrict__ o) {
    int b = blockIdx.x;
    int h = blockIdx.y;
    __shared__ float Ks[N_][DH_];
    __shared__ float Vs[N_][DH_];
    for (int e = threadIdx.x; e < N_ * DH_; e += 256) {
        int j = e >> 5, d = e & 31;
        const bf16* base = qkv + (size_t)(b * N_ + j) * (3 * INNER_);
        Ks[j][d] = b2f(base[INNER_ + h * DH_ + d]);
        Vs[j][d] = b2f(base[2 * INNER_ + h * DH_ + d]);
    }
    __syncthreads();
    int i = threadIdx.x;
    if (i >= N_) return;
    float q[DH_];
    const bf16* qp = qkv + (size_t)(b * N_ + i) * (3 * INNER_) + h * DH_;
#pragma unroll
    for (int d = 0; d < DH_; d++) q[d] = b2f(qp[d]);
    float sc = scale[h];
    float m = -1e30f;
    for (int j = 0; j < N_; j++) {
        if (j == i) continue;
        float s = 0.0f;
#pragma unroll
        for (int d = 0; d < DH_; d++) s += q[d] * Ks[j][d];
        m = fmaxf(m, s * sc);
    }
    float l = 0.0f;
    float acc[DH_];
#pragma unroll
    for (int d = 0; d < DH_; d++) acc[d] = 0.0f;
    for (int j = 0; j < N_; j++) {
        if (j == i) continue;
        float s = 0.0f;
#pragma unroll
        for (int d = 0; d < DH_; d++) s += q[d] * Ks[j][d];
        float w = __expf(s * sc - m);
        l += w;
#pragma unroll
        for (int d = 0; d < DH_; d++) acc[d] += w * Vs[j][d];
    }
    float inv = 1.0f / l;
    bf16* op = o + (size_t)(b * N_ + i) * INNER_ + h * DH_;
#pragma unroll
    for (int d = 0; d < DH_; d++) op[d] = f2b(acc[d] * inv);
}

// ------------------------------------------------------------------ diagnostics (f32 out)
// marker: base (1024+wsMB if ws too small) + 512 (NaN/inf in residual stream).
__global__ __launch_bounds__(256) void diag_kernel(const float* __restrict__ bufx,
                                                   float* __restrict__ outf,
                                                   int base_marker, int ran) {
    __shared__ int bad;
    if (threadIdx.x == 0) bad = 0;
    __syncthreads();
    if (ran) {
        for (int i = threadIdx.x; i < 4096; i += 256) {
            float v = bufx[i];
            if (!(fabsf(v) < 1e30f)) bad = 1;
        }
    }
    __syncthreads();
    int marker = base_marker + (bad ? 512 : 0);
    if (marker == 0) return;
    int idx = blockIdx.x * 256 + threadIdx.x;
    if (idx > 0 && idx < 64000) outf[idx] = 0.0f;
    if (idx == 0) outf[0] = (float)marker;
}

// ------------------------------------------------------------------ launch
extern "C" void kernel_launch(void* const* d_in, const int* in_sizes, int n_in,
                              void* d_out, int out_size, void* d_ws, size_t ws_size,
                              hipStream_t stream) {
    const float* img     = (const float*)d_in[0];
    const float* patch_w = (const float*)d_in[1];
    const float* patch_b = (const float*)d_in[2];
    const float* pos_emb = (const float*)d_in[3];
    const float* cls_tok = (const float*)d_in[4];
    const float* ln1_g   = (const float*)d_in[5];
    const float* ln1_b   = (const float*)d_in[6];
    const float* qkv_w   = (const float*)d_in[7];
    const float* scale   = (const float*)d_in[8];
    const float* out_w   = (const float*)d_in[9];
    const float* out_b   = (const float*)d_in[10];
    const float* ln2_g   = (const float*)d_in[11];
    const float* ln2_b   = (const float*)d_in[12];
    const float* ff_w1   = (const float*)d_in[13];
    const float* ff_b1   = (const float*)d_in[14];
    const float* ff_w2   = (const float*)d_in[15];
    const float* ff_b2   = (const float*)d_in[16];
    const float* lnf_g   = (const float*)d_in[17];
    const float* lnf_b   = (const float*)d_in[18];
    const float* head_w  = (const float*)d_in[19];
    const float* head_b  = (const float*)d_in[20];

    // Workspace layout (NEED = 58,146,816 B ~ 55.5 MB; proven to fit in round 2):
    //  buf_x  (f32) @ 0          : 19,365,888 B  residual stream [12608,384]
    //  buf_hb (bf16)@ 19,365,888 :  9,682,944 B  LN out / attn out / patch-embed out
    //  buf_cd (bf16)@ 29,048,832 : 29,048,832 B  qkv | patch-chunk + meanimg-bf16 | ff-mid chunk
    //  buf_cls(bf16)@ 58,097,664 :     49,152 B
    const size_t NEED = 58146816;
    char* ws = (char*)d_ws;
    float* buf_x   = (float*)ws;
    bf16*  buf_hb  = (bf16*)(ws + 19365888);
    bf16*  buf_cd  = (bf16*)(ws + 29048832);
    bf16*  meanimg = (bf16*)(ws + 29048832 + 22478848);
    bf16*  buf_cls = (bf16*)(ws + 58097664);

    if (ws_size < NEED) {
        diag_kernel<<<250, 256, 0, stream>>>((const float*)d_out, (float*)d_out,
                                             1024 + (int)(ws_size >> 20), 0);
        return;
    }

    // patch embed pipeline (patch matrix in two 6272-row chunks)
    mean_kernel<<<(B_ * 50176 + 255) / 256, 256, 0, stream>>>(img, meanimg);
    for (int c = 0; c < 2; c++) {
        int bp0 = c * 6272;
        patches_kernel<<<6272, 256, 0, stream>>>(img, meanimg, buf_cd, bp0);
        gemm_kernel<0, bf16><<<dim3(DIM_ / 64, 98), 256, 0, stream>>>(
            buf_cd, patch_w, patch_b, nullptr, buf_hb + (size_t)bp0 * DIM_, 6272, DIM_, PD_);
    }
    addpos_kernel<<<(B_ * N_ * DIM_ + 255) / 256, 256, 0, stream>>>(buf_hb, cls_tok, pos_emb, buf_x);

    const int ROWS = B_ * N_;  // 12608
    for (int i = 0; i < DEPTH_; i++) {
        ln_kernel<<<ROWS / 4, 256, 0, stream>>>(buf_x, DIM_, ln1_g + i * DIM_,
                                                ln1_b + i * DIM_, buf_hb, ROWS);
        gemm_kernel<0, bf16><<<dim3((3 * INNER_) / 64, ROWS / 64), 256, 0, stream>>>(
            buf_hb, qkv_w + (size_t)i * 3 * INNER_ * DIM_, nullptr, nullptr, buf_cd,
            ROWS, 3 * INNER_, DIM_);
        attn_kernel<<<dim3(B_, H_), 256, 0, stream>>>(buf_cd, scale + i * H_, buf_hb);
        gemm_kernel<1, float><<<dim3(DIM_ / 64, ROWS / 64), 256, 0, stream>>>(
            buf_hb, out_w + (size_t)i * DIM_ * INNER_, out_b + i * DIM_, buf_x, buf_x,
            ROWS, DIM_, INNER_);
        ln_kernel<<<ROWS / 4, 256, 0, stream>>>(buf_x, DIM_, ln2_g + i * DIM_,
                                                ln2_b + i * DIM_, buf_hb, ROWS);
        // FF in two row-chunks (6336 + 6272) to keep ff-mid within buf_cd
        int base = 0;
        for (int c = 0; c < 2; c++) {
            int mrows = (c == 0) ? 6336 : 6272;
            gemm_kernel<2, bf16><<<dim3(MLP_ / 64, mrows / 64), 256, 0, stream>>>(
                buf_hb + (size_t)base * DIM_, ff_w1 + (size_t)i * MLP_ * DIM_,
                ff_b1 + i * MLP_, nullptr, buf_cd, mrows, MLP_, DIM_);
            gemm_kernel<1, float><<<dim3(DIM_ / 64, mrows / 64), 256, 0, stream>>>(
                buf_cd, ff_w2 + (size_t)i * DIM_ * MLP_, ff_b2 + i * DIM_,
                buf_x + (size_t)base * DIM_, buf_x + (size_t)base * DIM_, mrows, DIM_, MLP_);
            base += mrows;
        }
    }

    ln_kernel<<<B_ / 4, 256, 0, stream>>>(buf_x, (long)N_ * DIM_, lnf_g, lnf_b, buf_cls, B_);
    // head -> f32 output
    gemm_kernel<0, float><<<dim3((NCLS_ + 63) / 64, 1), 256, 0, stream>>>(
        buf_cls, head_w, head_b, nullptr, (float*)d_out, B_, NCLS_, DIM_);

    diag_kernel<<<250, 256, 0, stream>>>(buf_x, (float*)d_out, 0, 1);
}

// Round 6
// 4453.149 us; speedup vs baseline: 3.6359x; 3.6359x over previous
//
#include <hip/hip_runtime.h>
#include <hip/hip_bf16.h>

// Model constants
#define B_ 64
#define IMG_ 224
#define P_ 16
#define G_ 14
#define NP_ 196
#define N_ 197
#define DIM_ 384
#define DEPTH_ 12
#define H_ 12
#define DH_ 32
#define INNER_ 384
#define MLP_ 1536
#define NCLS_ 1000
#define PD_ 1792
#define EPS_ 1e-5f

typedef __hip_bfloat16 bf16;
using bf16x8 = __attribute__((ext_vector_type(8))) short;   // 8 bf16 (4 VGPRs)
using f32x4  = __attribute__((ext_vector_type(4))) float;   // MFMA acc

__device__ __forceinline__ float b2f(bf16 x) { return __bfloat162float(x); }
__device__ __forceinline__ bf16 f2b(float x) { return __float2bfloat16(x); }
// raw RNE f32->bf16 (bit-level, avoids struct plumbing)
__device__ __forceinline__ short f2b_raw(float f) {
    unsigned x = __float_as_uint(f);
    unsigned r = (x + 0x7FFFu + ((x >> 16) & 1u)) >> 16;
    return (short)r;
}

// ---------------------------------------------------------------- mean image (bf16)
__global__ __launch_bounds__(256) void mean_kernel(const float* __restrict__ img,
                                                   bf16* __restrict__ meanimg) {
    int idx = blockIdx.x * 256 + threadIdx.x;
    if (idx >= B_ * 50176) return;
    int b = idx / 50176;
    int yx = idx - b * 50176;
    const float* p = img + (size_t)b * 3 * 50176 + yx;
    meanimg[idx] = f2b((p[0] + p[50176] + p[100352]) * (1.0f / 3.0f));
}

// ------------------------------------------------------------- patch matrix (chunk)
__global__ __launch_bounds__(256) void patches_kernel(const float* __restrict__ img,
                                                      const bf16* __restrict__ meanimg,
                                                      bf16* __restrict__ patches, int bp0) {
    int idx = blockIdx.x * 256 + threadIdx.x;
    if (idx >= 6272 * 256) return;
    int pix = idx & 255;
    int px = pix & 15, py = pix >> 4;
    int lbp = idx >> 8;
    int bp = bp0 + lbp;
    int p = bp % NP_;
    int b = bp / NP_;
    int gy = p / G_, gx = p - gy * G_;
    int y = gy * P_ + py, x = gx * P_ + px;
    const float* ib = img + (size_t)b * 3 * 50176 + y * 224 + x;
    bf16* out = patches + (size_t)lbp * PD_ + pix * 7;
    out[0] = f2b(ib[0]);
    out[1] = f2b(ib[50176]);
    out[2] = f2b(ib[100352]);
    const bf16* mb = meanimg + (size_t)b * 50176;
    out[3] = (x >= 8)  ? mb[y * 224 + x - 8]   : f2b(0.0f);   // l2
    out[4] = (x < 216) ? mb[y * 224 + x + 8]   : f2b(0.0f);   // r2
    out[5] = (y >= 8)  ? mb[(y - 8) * 224 + x] : f2b(0.0f);   // t2
    out[6] = (y < 216) ? mb[(y + 8) * 224 + x] : f2b(0.0f);   // b2
}

// --------------------------------------------------- cls + pos_emb assembly
__global__ __launch_bounds__(256) void addpos_kernel(const bf16* __restrict__ pe,
                                                     const float* __restrict__ cls_tok,
                                                     const float* __restrict__ pos_emb,
                                                     float* __restrict__ x) {
    int idx = blockIdx.x * 256 + threadIdx.x;
    if (idx >= B_ * N_ * DIM_) return;
    int c = idx % DIM_;
    int r = idx / DIM_;
    int t = r % N_;
    int b = r / N_;
    float v = (t == 0) ? cls_tok[c]
                       : b2f(pe[((size_t)(b * NP_ + t - 1)) * DIM_ + c]);
    x[idx] = v + pos_emb[t * DIM_ + c];
}

// ------------------------------------------------------------------ layernorm
__global__ __launch_bounds__(256) void ln_kernel(const float* __restrict__ in,
                                                 long in_stride,
                                                 const float* __restrict__ g,
                                                 const float* __restrict__ bb,
                                                 bf16* __restrict__ out, int rows) {
    int wave = threadIdx.x >> 6;
    int lane = threadIdx.x & 63;
    int row = blockIdx.x * 4 + wave;
    if (row >= rows) return;
    const float* p = in + (size_t)row * in_stride;
    float v[6];
    float s = 0.0f, s2 = 0.0f;
#pragma unroll
    for (int i = 0; i < 6; i++) {
        v[i] = p[lane + 64 * i];
        s += v[i];
        s2 += v[i] * v[i];
    }
#pragma unroll
    for (int m = 32; m >= 1; m >>= 1) {
        s += __shfl_xor(s, m);
        s2 += __shfl_xor(s2, m);
    }
    float mu = s * (1.0f / 384.0f);
    float var = s2 * (1.0f / 384.0f) - mu * mu;
    var = fmaxf(var, 0.0f);
    float inv = rsqrtf(var + EPS_);
    bf16* q = out + (size_t)row * DIM_;
#pragma unroll
    for (int i = 0; i < 6; i++) {
        int c = lane + 64 * i;
        q[c] = f2b((v[i] - mu) * inv * g[c] + bb[c]);
    }
}

// ------------------------------------------------------------------ MFMA GEMM
// C[M,N] = A[M,K] @ W[N,K]^T (+bias) (+res) (gelu). A bf16, W f32 (converted on the fly).
// Tile: BM=128, BN=64, BK=32. 4 waves; wave w computes rows [w*32, w*32+32).
// MODE 0: bias. 1: bias+res(f32). 2: bias+exact GELU.
template <int MODE, typename OutT>
__global__ __launch_bounds__(256) void mgemm_kernel(const bf16* __restrict__ A,
                                                    const float* __restrict__ W,
                                                    const float* __restrict__ bias,
                                                    const float* __restrict__ res,
                                                    OutT* __restrict__ C,
                                                    int M, int N, int K) {
    __shared__ __align__(16) short lds_a[128 * 32];  // 8 KB
    __shared__ __align__(16) short lds_b[64 * 32];   // 4 KB
    int tid = threadIdx.x;
    int rowBase = blockIdx.y * 128;
    int colBase = blockIdx.x * 64;
    int w = tid >> 6, lane = tid & 63;
    int ml = lane & 15, kseg = lane >> 4;

    // staging indices
    int ar = tid >> 1;            // 0..127 (A tile row)
    int ah = (tid & 1) * 16;      // bf16 offset within row: 0 / 16
    int agr = rowBase + ar;
    if (agr > M - 1) agr = M - 1; // clamp (stores predicated)
    const float4* asrc_base = (const float4*)(A + (size_t)agr * K + ah);
    int br = tid >> 2;            // 0..63 (W tile row)
    int bs = (tid & 3) * 8;       // float offset within row
    const float4* wsrc_base = (const float4*)(W + (size_t)(colBase + br) * K + bs);

    f32x4 acc[2][4] = {};

    for (int k0 = 0; k0 < K; k0 += 32) {
        // A: 32 B per thread (16 bf16)
        const float4* asrc = (const float4*)((const bf16*)asrc_base + k0);
        float4 av0 = asrc[0];
        float4 av1 = asrc[1];
        // W: 8 floats per thread -> 8 bf16
        const float4* wsrc = (const float4*)((const float*)wsrc_base + k0);
        float4 w0 = wsrc[0];
        float4 w1 = wsrc[1];
        bf16x8 wb;
        wb[0] = f2b_raw(w0.x); wb[1] = f2b_raw(w0.y);
        wb[2] = f2b_raw(w0.z); wb[3] = f2b_raw(w0.w);
        wb[4] = f2b_raw(w1.x); wb[5] = f2b_raw(w1.y);
        wb[6] = f2b_raw(w1.z); wb[7] = f2b_raw(w1.w);
        __syncthreads();   // protect LDS from previous iteration's readers
        *(float4*)(lds_a + ar * 32 + ah) = av0;
        *(float4*)(lds_a + ar * 32 + ah + 8) = av1;
        *(bf16x8*)(lds_b + br * 32 + bs) = wb;
        __syncthreads();
        // fragments
        bf16x8 af0 = *(const bf16x8*)(lds_a + (w * 32 + ml) * 32 + kseg * 8);
        bf16x8 af1 = *(const bf16x8*)(lds_a + (w * 32 + 16 + ml) * 32 + kseg * 8);
#pragma unroll
        for (int ct = 0; ct < 4; ct++) {
            bf16x8 bf = *(const bf16x8*)(lds_b + (ct * 16 + ml) * 32 + kseg * 8);
            acc[0][ct] = __builtin_amdgcn_mfma_f32_16x16x32_bf16(af0, bf, acc[0][ct], 0, 0, 0);
            acc[1][ct] = __builtin_amdgcn_mfma_f32_16x16x32_bf16(af1, bf, acc[1][ct], 0, 0, 0);
        }
    }

    float bval[4];
#pragma unroll
    for (int ct = 0; ct < 4; ct++)
        bval[ct] = bias ? bias[colBase + ct * 16 + ml] : 0.0f;

#pragma unroll
    for (int rt = 0; rt < 2; rt++) {
#pragma unroll
        for (int reg = 0; reg < 4; reg++) {
            int r = rowBase + w * 32 + rt * 16 + kseg * 4 + reg;
            if (r >= M) continue;
            size_t ro = (size_t)r * N;
#pragma unroll
            for (int ct = 0; ct < 4; ct++) {
                int c = colBase + ct * 16 + ml;
                float v = acc[rt][ct][reg] + bval[ct];
                if constexpr (MODE == 1) v += res[ro + c];
                if constexpr (MODE == 2) v = 0.5f * v * (1.0f + erff(v * 0.70710678118f));
                C[ro + c] = (OutT)v;
            }
        }
    }
}

// ------------------------------------------------------------------ VALU GEMM (head only)
template <int MODE, typename OutT>
__global__ __launch_bounds__(256) void gemm_kernel(const bf16* __restrict__ A,
                                                   const float* __restrict__ W,
                                                   const float* __restrict__ bias,
                                                   const float* res, OutT* C,
                                                   int M, int N, int K) {
    __shared__ float As[32][65];
    __shared__ float Ws[32][65];
    int tid = threadIdx.x;
    int rowBase = blockIdx.y * 64;
    int colBase = blockIdx.x * 64;
    int lr = tid >> 2;
    int lk = (tid & 3) * 8;
    int tx = tid & 15, ty = tid >> 4;
    float acc[4][4] = {};
    for (int k0 = 0; k0 < K; k0 += 32) {
        int gr = rowBase + lr;
        const bf16* asrc = A + (size_t)gr * K + k0 + lk;
        bool aok = (gr < M);
#pragma unroll
        for (int e = 0; e < 8; e++) As[lk + e][lr] = aok ? b2f(asrc[e]) : 0.0f;
        int gc = colBase + lr;
        const float* wsrc = W + (size_t)gc * K + k0 + lk;
        bool wok = (gc < N);
#pragma unroll
        for (int e = 0; e < 8; e++) Ws[lk + e][lr] = wok ? wsrc[e] : 0.0f;
        __syncthreads();
#pragma unroll
        for (int kk = 0; kk < 32; kk++) {
            float a[4], b[4];
#pragma unroll
            for (int i = 0; i < 4; i++) a[i] = As[kk][ty * 4 + i];
#pragma unroll
            for (int j = 0; j < 4; j++) b[j] = Ws[kk][tx * 4 + j];
#pragma unroll
            for (int i = 0; i < 4; i++)
#pragma unroll
                for (int j = 0; j < 4; j++) acc[i][j] += a[i] * b[j];
        }
        __syncthreads();
    }
#pragma unroll
    for (int i = 0; i < 4; i++) {
        int r = rowBase + ty * 4 + i;
        if (r >= M) continue;
#pragma unroll
        for (int j = 0; j < 4; j++) {
            int c = colBase + tx * 4 + j;
            if (c >= N) continue;
            float v = acc[i][j];
            if (bias) v += bias[c];
            if constexpr (MODE == 1) v += res[(size_t)r * N + c];
            if constexpr (MODE == 2) v = 0.5f * v * (1.0f + erff(v * 0.70710678118f));
            C[(size_t)r * N + c] = (OutT)v;
        }
    }
}

// ------------------------------------------------------------------ attention
__global__ __launch_bounds__(256) void attn_kernel(const bf16* __restrict__ qkv,
                                                   const float* __restrict__ scale,
                                                   bf16* __restrict__ o) {
    int b = blockIdx.x;
    int h = blockIdx.y;
    __shared__ float Ks[N_][DH_];
    __shared__ float Vs[N_][DH_];
    for (int e = threadIdx.x; e < N_ * DH_; e += 256) {
        int j = e >> 5, d = e & 31;
        const bf16* base = qkv + (size_t)(b * N_ + j) * (3 * INNER_);
        Ks[j][d] = b2f(base[INNER_ + h * DH_ + d]);
        Vs[j][d] = b2f(base[2 * INNER_ + h * DH_ + d]);
    }
    __syncthreads();
    int i = threadIdx.x;
    if (i >= N_) return;
    float q[DH_];
    const bf16* qp = qkv + (size_t)(b * N_ + i) * (3 * INNER_) + h * DH_;
#pragma unroll
    for (int d = 0; d < DH_; d++) q[d] = b2f(qp[d]);
    float sc = scale[h];
    float m = -1e30f;
    for (int j = 0; j < N_; j++) {
        if (j == i) continue;
        float s = 0.0f;
#pragma unroll
        for (int d = 0; d < DH_; d++) s += q[d] * Ks[j][d];
        m = fmaxf(m, s * sc);
    }
    float l = 0.0f;
    float acc[DH_];
#pragma unroll
    for (int d = 0; d < DH_; d++) acc[d] = 0.0f;
    for (int j = 0; j < N_; j++) {
        if (j == i) continue;
        float s = 0.0f;
#pragma unroll
        for (int d = 0; d < DH_; d++) s += q[d] * Ks[j][d];
        float w = __expf(s * sc - m);
        l += w;
#pragma unroll
        for (int d = 0; d < DH_; d++) acc[d] += w * Vs[j][d];
    }
    float inv = 1.0f / l;
    bf16* op = o + (size_t)(b * N_ + i) * INNER_ + h * DH_;
#pragma unroll
    for (int d = 0; d < DH_; d++) op[d] = f2b(acc[d] * inv);
}

// ------------------------------------------------------------------ diagnostics (f32 out)
__global__ __launch_bounds__(256) void diag_kernel(const float* __restrict__ bufx,
                                                   float* __restrict__ outf,
                                                   int base_marker, int ran) {
    __shared__ int bad;
    if (threadIdx.x == 0) bad = 0;
    __syncthreads();
    if (ran) {
        for (int i = threadIdx.x; i < 4096; i += 256) {
            float v = bufx[i];
            if (!(fabsf(v) < 1e30f)) bad = 1;
        }
    }
    __syncthreads();
    int marker = base_marker + (bad ? 512 : 0);
    if (marker == 0) return;
    int idx = blockIdx.x * 256 + threadIdx.x;
    if (idx > 0 && idx < 64000) outf[idx] = 0.0f;
    if (idx == 0) outf[0] = (float)marker;
}

// ------------------------------------------------------------------ launch
extern "C" void kernel_launch(void* const* d_in, const int* in_sizes, int n_in,
                              void* d_out, int out_size, void* d_ws, size_t ws_size,
                              hipStream_t stream) {
    const float* img     = (const float*)d_in[0];
    const float* patch_w = (const float*)d_in[1];
    const float* patch_b = (const float*)d_in[2];
    const float* pos_emb = (const float*)d_in[3];
    const float* cls_tok = (const float*)d_in[4];
    const float* ln1_g   = (const float*)d_in[5];
    const float* ln1_b   = (const float*)d_in[6];
    const float* qkv_w   = (const float*)d_in[7];
    const float* scale   = (const float*)d_in[8];
    const float* out_w   = (const float*)d_in[9];
    const float* out_b   = (const float*)d_in[10];
    const float* ln2_g   = (const float*)d_in[11];
    const float* ln2_b   = (const float*)d_in[12];
    const float* ff_w1   = (const float*)d_in[13];
    const float* ff_b1   = (const float*)d_in[14];
    const float* ff_w2   = (const float*)d_in[15];
    const float* ff_b2   = (const float*)d_in[16];
    const float* lnf_g   = (const float*)d_in[17];
    const float* lnf_b   = (const float*)d_in[18];
    const float* head_w  = (const float*)d_in[19];
    const float* head_b  = (const float*)d_in[20];

    // Workspace layout (NEED = 58,146,816 B ~ 55.5 MB; proven to fit in round 2):
    const size_t NEED = 58146816;
    char* ws = (char*)d_ws;
    float* buf_x   = (float*)ws;
    bf16*  buf_hb  = (bf16*)(ws + 19365888);
    bf16*  buf_cd  = (bf16*)(ws + 29048832);
    bf16*  meanimg = (bf16*)(ws + 29048832 + 22478848);
    bf16*  buf_cls = (bf16*)(ws + 58097664);

    if (ws_size < NEED) {
        diag_kernel<<<250, 256, 0, stream>>>((const float*)d_out, (float*)d_out,
                                             1024 + (int)(ws_size >> 20), 0);
        return;
    }

    // patch embed pipeline (patch matrix in two 6272-row chunks)
    mean_kernel<<<(B_ * 50176 + 255) / 256, 256, 0, stream>>>(img, meanimg);
    for (int c = 0; c < 2; c++) {
        int bp0 = c * 6272;
        patches_kernel<<<6272, 256, 0, stream>>>(img, meanimg, buf_cd, bp0);
        mgemm_kernel<0, bf16><<<dim3(DIM_ / 64, 49), 256, 0, stream>>>(
            buf_cd, patch_w, patch_b, nullptr, buf_hb + (size_t)bp0 * DIM_, 6272, DIM_, PD_);
    }
    addpos_kernel<<<(B_ * N_ * DIM_ + 255) / 256, 256, 0, stream>>>(buf_hb, cls_tok, pos_emb, buf_x);

    const int ROWS = B_ * N_;  // 12608
    const int GY = (ROWS + 127) / 128;  // 99
    for (int i = 0; i < DEPTH_; i++) {
        ln_kernel<<<ROWS / 4, 256, 0, stream>>>(buf_x, DIM_, ln1_g + i * DIM_,
                                                ln1_b + i * DIM_, buf_hb, ROWS);
        mgemm_kernel<0, bf16><<<dim3((3 * INNER_) / 64, GY), 256, 0, stream>>>(
            buf_hb, qkv_w + (size_t)i * 3 * INNER_ * DIM_, nullptr, nullptr, buf_cd,
            ROWS, 3 * INNER_, DIM_);
        attn_kernel<<<dim3(B_, H_), 256, 0, stream>>>(buf_cd, scale + i * H_, buf_hb);
        mgemm_kernel<1, float><<<dim3(DIM_ / 64, GY), 256, 0, stream>>>(
            buf_hb, out_w + (size_t)i * DIM_ * INNER_, out_b + i * DIM_, buf_x, buf_x,
            ROWS, DIM_, INNER_);
        ln_kernel<<<ROWS / 4, 256, 0, stream>>>(buf_x, DIM_, ln2_g + i * DIM_,
                                                ln2_b + i * DIM_, buf_hb, ROWS);
        // FF in two row-chunks (6336 + 6272) to keep ff-mid within buf_cd
        int base = 0;
        for (int c = 0; c < 2; c++) {
            int mrows = (c == 0) ? 6336 : 6272;
            int gy = (mrows + 127) / 128;
            mgemm_kernel<2, bf16><<<dim3(MLP_ / 64, gy), 256, 0, stream>>>(
                buf_hb + (size_t)base * DIM_, ff_w1 + (size_t)i * MLP_ * DIM_,
                ff_b1 + i * MLP_, nullptr, buf_cd, mrows, MLP_, DIM_);
            mgemm_kernel<1, float><<<dim3(DIM_ / 64, gy), 256, 0, stream>>>(
                buf_cd, ff_w2 + (size_t)i * DIM_ * MLP_, ff_b2 + i * DIM_,
                buf_x + (size_t)base * DIM_, buf_x + (size_t)base * DIM_, mrows, DIM_, MLP_);
            base += mrows;
        }
    }

    ln_kernel<<<B_ / 4, 256, 0, stream>>>(buf_x, (long)N_ * DIM_, lnf_g, lnf_b, buf_cls, B_);
    gemm_kernel<0, float><<<dim3((NCLS_ + 63) / 64, 1), 256, 0, stream>>>(
        buf_cls, head_w, head_b, nullptr, (float*)d_out, B_, NCLS_, DIM_);

    diag_kernel<<<250, 256, 0, stream>>>(buf_x, (float*)d_out, 0, 1);
}

// Round 7
// 3201.723 us; speedup vs baseline: 5.0570x; 1.3909x over previous
//
#include <hip/hip_runtime.h>
#include <hip/hip_bf16.h>

// Model constants
#define B_ 64
#define IMG_ 224
#define P_ 16
#define G_ 14
#define NP_ 196
#define N_ 197
#define DIM_ 384
#define DEPTH_ 12
#define H_ 12
#define DH_ 32
#define INNER_ 384
#define MLP_ 1536
#define NCLS_ 1000
#define PD_ 1792
#define EPS_ 1e-5f

typedef __hip_bfloat16 bf16;
using bf16x8 = __attribute__((ext_vector_type(8))) short;   // 8 bf16 (4 VGPRs)
using f32x4  = __attribute__((ext_vector_type(4))) float;   // MFMA acc

__device__ __forceinline__ float b2f(bf16 x) { return __bfloat162float(x); }
__device__ __forceinline__ bf16 f2b(float x) { return __float2bfloat16(x); }
// raw RNE f32->bf16 (bit-level)
__device__ __forceinline__ short f2b_raw(float f) {
    unsigned x = __float_as_uint(f);
    unsigned r = (x + 0x7FFFu + ((x >> 16) & 1u)) >> 16;
    return (short)r;
}

// ---------------------------------------------------------------- mean image (bf16)
__global__ __launch_bounds__(256) void mean_kernel(const float* __restrict__ img,
                                                   bf16* __restrict__ meanimg) {
    int idx = blockIdx.x * 256 + threadIdx.x;
    if (idx >= B_ * 50176) return;
    int b = idx / 50176;
    int yx = idx - b * 50176;
    const float* p = img + (size_t)b * 3 * 50176 + yx;
    meanimg[idx] = f2b((p[0] + p[50176] + p[100352]) * (1.0f / 3.0f));
}

// ------------------------------------------------------------- patch matrix (chunk)
__global__ __launch_bounds__(256) void patches_kernel(const float* __restrict__ img,
                                                      const bf16* __restrict__ meanimg,
                                                      bf16* __restrict__ patches, int bp0) {
    int idx = blockIdx.x * 256 + threadIdx.x;
    if (idx >= 6272 * 256) return;
    int pix = idx & 255;
    int px = pix & 15, py = pix >> 4;
    int lbp = idx >> 8;
    int bp = bp0 + lbp;
    int p = bp % NP_;
    int b = bp / NP_;
    int gy = p / G_, gx = p - gy * G_;
    int y = gy * P_ + py, x = gx * P_ + px;
    const float* ib = img + (size_t)b * 3 * 50176 + y * 224 + x;
    bf16* out = patches + (size_t)lbp * PD_ + pix * 7;
    out[0] = f2b(ib[0]);
    out[1] = f2b(ib[50176]);
    out[2] = f2b(ib[100352]);
    const bf16* mb = meanimg + (size_t)b * 50176;
    out[3] = (x >= 8)  ? mb[y * 224 + x - 8]   : f2b(0.0f);   // l2
    out[4] = (x < 216) ? mb[y * 224 + x + 8]   : f2b(0.0f);   // r2
    out[5] = (y >= 8)  ? mb[(y - 8) * 224 + x] : f2b(0.0f);   // t2
    out[6] = (y < 216) ? mb[(y + 8) * 224 + x] : f2b(0.0f);   // b2
}

// --------------------------------------------------- cls + pos_emb assembly
__global__ __launch_bounds__(256) void addpos_kernel(const bf16* __restrict__ pe,
                                                     const float* __restrict__ cls_tok,
                                                     const float* __restrict__ pos_emb,
                                                     float* __restrict__ x) {
    int idx = blockIdx.x * 256 + threadIdx.x;
    if (idx >= B_ * N_ * DIM_) return;
    int c = idx % DIM_;
    int r = idx / DIM_;
    int t = r % N_;
    int b = r / N_;
    float v = (t == 0) ? cls_tok[c]
                       : b2f(pe[((size_t)(b * NP_ + t - 1)) * DIM_ + c]);
    x[idx] = v + pos_emb[t * DIM_ + c];
}

// ------------------------------------------------------------------ layernorm
__global__ __launch_bounds__(256) void ln_kernel(const float* __restrict__ in,
                                                 long in_stride,
                                                 const float* __restrict__ g,
                                                 const float* __restrict__ bb,
                                                 bf16* __restrict__ out, int rows) {
    int wave = threadIdx.x >> 6;
    int lane = threadIdx.x & 63;
    int row = blockIdx.x * 4 + wave;
    if (row >= rows) return;
    const float* p = in + (size_t)row * in_stride;
    float v[6];
    float s = 0.0f, s2 = 0.0f;
#pragma unroll
    for (int i = 0; i < 6; i++) {
        v[i] = p[lane + 64 * i];
        s += v[i];
        s2 += v[i] * v[i];
    }
#pragma unroll
    for (int m = 32; m >= 1; m >>= 1) {
        s += __shfl_xor(s, m);
        s2 += __shfl_xor(s2, m);
    }
    float mu = s * (1.0f / 384.0f);
    float var = s2 * (1.0f / 384.0f) - mu * mu;
    var = fmaxf(var, 0.0f);
    float inv = rsqrtf(var + EPS_);
    bf16* q = out + (size_t)row * DIM_;
#pragma unroll
    for (int i = 0; i < 6; i++) {
        int c = lane + 64 * i;
        q[c] = f2b((v[i] - mu) * inv * g[c] + bb[c]);
    }
}

// ------------------------------------------------------------------ MFMA GEMM
// C[M,N] = A[M,K] @ W[N,K]^T (+bias) (+res) (gelu). A bf16, W f32 (converted on the fly).
// Tile: BM=128, BN=64, BK=32. MODE 0: bias. 1: bias+res(f32). 2: bias+exact GELU.
template <int MODE, typename OutT>
__global__ __launch_bounds__(256) void mgemm_kernel(const bf16* __restrict__ A,
                                                    const float* __restrict__ W,
                                                    const float* __restrict__ bias,
                                                    const float* __restrict__ res,
                                                    OutT* __restrict__ C,
                                                    int M, int N, int K) {
    __shared__ __align__(16) short lds_a[128 * 32];  // 8 KB
    __shared__ __align__(16) short lds_b[64 * 32];   // 4 KB
    int tid = threadIdx.x;
    int rowBase = blockIdx.y * 128;
    int colBase = blockIdx.x * 64;
    int w = tid >> 6, lane = tid & 63;
    int ml = lane & 15, kseg = lane >> 4;

    int ar = tid >> 1;
    int ah = (tid & 1) * 16;
    int agr = rowBase + ar;
    if (agr > M - 1) agr = M - 1;
    const float4* asrc_base = (const float4*)(A + (size_t)agr * K + ah);
    int br = tid >> 2;
    int bs = (tid & 3) * 8;
    const float4* wsrc_base = (const float4*)(W + (size_t)(colBase + br) * K + bs);

    f32x4 acc[2][4] = {};

    for (int k0 = 0; k0 < K; k0 += 32) {
        const float4* asrc = (const float4*)((const bf16*)asrc_base + k0);
        float4 av0 = asrc[0];
        float4 av1 = asrc[1];
        const float4* wsrc = (const float4*)((const float*)wsrc_base + k0);
        float4 w0 = wsrc[0];
        float4 w1 = wsrc[1];
        bf16x8 wb;
        wb[0] = f2b_raw(w0.x); wb[1] = f2b_raw(w0.y);
        wb[2] = f2b_raw(w0.z); wb[3] = f2b_raw(w0.w);
        wb[4] = f2b_raw(w1.x); wb[5] = f2b_raw(w1.y);
        wb[6] = f2b_raw(w1.z); wb[7] = f2b_raw(w1.w);
        __syncthreads();
        *(float4*)(lds_a + ar * 32 + ah) = av0;
        *(float4*)(lds_a + ar * 32 + ah + 8) = av1;
        *(bf16x8*)(lds_b + br * 32 + bs) = wb;
        __syncthreads();
        bf16x8 af0 = *(const bf16x8*)(lds_a + (w * 32 + ml) * 32 + kseg * 8);
        bf16x8 af1 = *(const bf16x8*)(lds_a + (w * 32 + 16 + ml) * 32 + kseg * 8);
#pragma unroll
        for (int ct = 0; ct < 4; ct++) {
            bf16x8 bf = *(const bf16x8*)(lds_b + (ct * 16 + ml) * 32 + kseg * 8);
            acc[0][ct] = __builtin_amdgcn_mfma_f32_16x16x32_bf16(af0, bf, acc[0][ct], 0, 0, 0);
            acc[1][ct] = __builtin_amdgcn_mfma_f32_16x16x32_bf16(af1, bf, acc[1][ct], 0, 0, 0);
        }
    }

    float bval[4];
#pragma unroll
    for (int ct = 0; ct < 4; ct++)
        bval[ct] = bias ? bias[colBase + ct * 16 + ml] : 0.0f;

#pragma unroll
    for (int rt = 0; rt < 2; rt++) {
#pragma unroll
        for (int reg = 0; reg < 4; reg++) {
            int r = rowBase + w * 32 + rt * 16 + kseg * 4 + reg;
            if (r >= M) continue;
            size_t ro = (size_t)r * N;
#pragma unroll
            for (int ct = 0; ct < 4; ct++) {
                int c = colBase + ct * 16 + ml;
                float v = acc[rt][ct][reg] + bval[ct];
                if constexpr (MODE == 1) v += res[ro + c];
                if constexpr (MODE == 2) v = 0.5f * v * (1.0f + erff(v * 0.70710678118f));
                C[ro + c] = (OutT)v;
            }
        }
    }
}

// ------------------------------------------------------------------ VALU GEMM (head only)
template <int MODE, typename OutT>
__global__ __launch_bounds__(256) void gemm_kernel(const bf16* __restrict__ A,
                                                   const float* __restrict__ W,
                                                   const float* __restrict__ bias,
                                                   const float* res, OutT* C,
                                                   int M, int N, int K) {
    __shared__ float As[32][65];
    __shared__ float Ws[32][65];
    int tid = threadIdx.x;
    int rowBase = blockIdx.y * 64;
    int colBase = blockIdx.x * 64;
    int lr = tid >> 2;
    int lk = (tid & 3) * 8;
    int tx = tid & 15, ty = tid >> 4;
    float acc[4][4] = {};
    for (int k0 = 0; k0 < K; k0 += 32) {
        int gr = rowBase + lr;
        const bf16* asrc = A + (size_t)gr * K + k0 + lk;
        bool aok = (gr < M);
#pragma unroll
        for (int e = 0; e < 8; e++) As[lk + e][lr] = aok ? b2f(asrc[e]) : 0.0f;
        int gc = colBase + lr;
        const float* wsrc = W + (size_t)gc * K + k0 + lk;
        bool wok = (gc < N);
#pragma unroll
        for (int e = 0; e < 8; e++) Ws[lk + e][lr] = wok ? wsrc[e] : 0.0f;
        __syncthreads();
#pragma unroll
        for (int kk = 0; kk < 32; kk++) {
            float a[4], b[4];
#pragma unroll
            for (int i = 0; i < 4; i++) a[i] = As[kk][ty * 4 + i];
#pragma unroll
            for (int j = 0; j < 4; j++) b[j] = Ws[kk][tx * 4 + j];
#pragma unroll
            for (int i = 0; i < 4; i++)
#pragma unroll
                for (int j = 0; j < 4; j++) acc[i][j] += a[i] * b[j];
        }
        __syncthreads();
    }
#pragma unroll
    for (int i = 0; i < 4; i++) {
        int r = rowBase + ty * 4 + i;
        if (r >= M) continue;
#pragma unroll
        for (int j = 0; j < 4; j++) {
            int c = colBase + tx * 4 + j;
            if (c >= N) continue;
            float v = acc[i][j];
            if (bias) v += bias[c];
            if constexpr (MODE == 1) v += res[(size_t)r * N + c];
            if constexpr (MODE == 2) v = 0.5f * v * (1.0f + erff(v * 0.70710678118f));
            C[(size_t)r * N + c] = (OutT)v;
        }
    }
}

// ------------------------------------------------------------------ MFMA attention
// One block per (b,h), 4 waves. K in LDS rows (208x32, zero-padded), V transposed
// Vt[d][key] (stride 232). Per-wave 16-row Q-tiles: S = QK^T (13 MFMAs), masked
// softmax via quad-group shfl_xor, P -> per-wave LDS (C-layout -> A-layout), O = PV.
#define AKR 208
#define VTS 232
#define PSS 232
__global__ __launch_bounds__(256) void attn_mfma_kernel(const bf16* __restrict__ qkv,
                                                        const float* __restrict__ scale,
                                                        bf16* __restrict__ o) {
    __shared__ __align__(16) short Ks[AKR * 32];        // 13312 B
    __shared__ __align__(16) short Vt[32 * VTS];        // 14848 B
    __shared__ __align__(16) short Ps[4][16 * PSS];     // 29696 B
    int b = blockIdx.x, h = blockIdx.y;
    int tid = threadIdx.x;
    int w = tid >> 6, lane = tid & 63;
    int ml = lane & 15, quad = lane >> 4;

    // zero Vt (padding cols must be 0: garbage*0 in PV would still NaN)
    for (int i = tid; i < 32 * VTS / 2; i += 256) ((int*)Vt)[i] = 0;
    // zero own wave's Ps cols 208..223 (PV k-chunks read up to col 223)
    for (int e = lane; e < 16 * 16; e += 64) {
        int r = e >> 4, c = e & 15;
        Ps[w][r * PSS + 208 + c] = 0;
    }
    __syncthreads();
    // fill Ks rows 0..207 (>=197 zero)
    for (int e = tid; e < AKR * 4; e += 256) {
        int row = e >> 2, seg = e & 3;
        float4 v = {0.0f, 0.0f, 0.0f, 0.0f};
        if (row < N_)
            v = *(const float4*)(qkv + (size_t)(b * N_ + row) * (3 * INNER_) + INNER_ + h * DH_ + seg * 8);
        *(float4*)(Ks + row * 32 + seg * 8) = v;
    }
    // fill Vt (transpose; coalesced reads, strided LDS writes)
    for (int e = tid; e < N_ * 32; e += 256) {
        int j = e >> 5, d = e & 31;
        Vt[d * VTS + j] = *(const short*)(qkv + (size_t)(b * N_ + j) * (3 * INNER_) + 2 * INNER_ + h * DH_ + d);
    }
    __syncthreads();

    float sc = scale[h];
    for (int qt = w; qt < 13; qt += 4) {
        int q0 = qt * 16;
        int qrow = q0 + ml;
        if (qrow > N_ - 1) qrow = N_ - 1;   // clamp; stores predicated
        bf16x8 aq = *(const bf16x8*)(qkv + (size_t)(b * N_ + qrow) * (3 * INNER_) + h * DH_ + quad * 8);
        // S = Q K^T
        f32x4 accs[13];
#pragma unroll
        for (int kt = 0; kt < 13; kt++) {
            bf16x8 bk = *(const bf16x8*)(Ks + (kt * 16 + ml) * 32 + quad * 8);
            f32x4 z = {0.0f, 0.0f, 0.0f, 0.0f};
            accs[kt] = __builtin_amdgcn_mfma_f32_16x16x32_bf16(aq, bk, z, 0, 0, 0);
        }
        // mask + scale + row max
        float rmax[4] = {-1e30f, -1e30f, -1e30f, -1e30f};
#pragma unroll
        for (int kt = 0; kt < 13; kt++) {
            int key = kt * 16 + ml;
#pragma unroll
            for (int reg = 0; reg < 4; reg++) {
                int qg = q0 + quad * 4 + reg;
                bool valid = (key < N_) && (key != qg);
                float s = valid ? accs[kt][reg] * sc : -1e30f;
                accs[kt][reg] = s;
                rmax[reg] = fmaxf(rmax[reg], s);
            }
        }
#pragma unroll
        for (int m = 1; m <= 8; m <<= 1)
#pragma unroll
            for (int reg = 0; reg < 4; reg++)
                rmax[reg] = fmaxf(rmax[reg], __shfl_xor(rmax[reg], m));
        // exp + row sum
        float rsum[4] = {0.0f, 0.0f, 0.0f, 0.0f};
#pragma unroll
        for (int kt = 0; kt < 13; kt++) {
#pragma unroll
            for (int reg = 0; reg < 4; reg++) {
                float wgt = __expf(accs[kt][reg] - rmax[reg]);  // masked -> exp(-huge)=0
                accs[kt][reg] = wgt;
                rsum[reg] += wgt;
            }
        }
#pragma unroll
        for (int m = 1; m <= 8; m <<= 1)
#pragma unroll
            for (int reg = 0; reg < 4; reg++)
                rsum[reg] += __shfl_xor(rsum[reg], m);
        // P -> LDS (C-layout scatter; bf16)
#pragma unroll
        for (int kt = 0; kt < 13; kt++)
#pragma unroll
            for (int reg = 0; reg < 4; reg++)
                Ps[w][(quad * 4 + reg) * PSS + kt * 16 + ml] = f2b_raw(accs[kt][reg]);
        // O = P V
        f32x4 acco[2] = {{0.0f, 0.0f, 0.0f, 0.0f}, {0.0f, 0.0f, 0.0f, 0.0f}};
#pragma unroll
        for (int kc = 0; kc < 7; kc++) {
            bf16x8 ap = *(const bf16x8*)(Ps[w] + ml * PSS + kc * 32 + quad * 8);
#pragma unroll
            for (int nt = 0; nt < 2; nt++) {
                bf16x8 bv = *(const bf16x8*)(Vt + (nt * 16 + ml) * VTS + kc * 32 + quad * 8);
                acco[nt] = __builtin_amdgcn_mfma_f32_16x16x32_bf16(ap, bv, acco[nt], 0, 0, 0);
            }
        }
        // store (divide by row sum)
#pragma unroll
        for (int reg = 0; reg < 4; reg++) {
            int qg = q0 + quad * 4 + reg;
            if (qg >= N_) continue;
            float inv = 1.0f / rsum[reg];
#pragma unroll
            for (int nt = 0; nt < 2; nt++)
                o[(size_t)(b * N_ + qg) * INNER_ + h * DH_ + nt * 16 + ml] = f2b(acco[nt][reg] * inv);
        }
    }
}

// ------------------------------------------------------------------ diagnostics (f32 out)
__global__ __launch_bounds__(256) void diag_kernel(const float* __restrict__ bufx,
                                                   float* __restrict__ outf,
                                                   int base_marker, int ran) {
    __shared__ int bad;
    if (threadIdx.x == 0) bad = 0;
    __syncthreads();
    if (ran) {
        for (int i = threadIdx.x; i < 4096; i += 256) {
            float v = bufx[i];
            if (!(fabsf(v) < 1e30f)) bad = 1;
        }
    }
    __syncthreads();
    int marker = base_marker + (bad ? 512 : 0);
    if (marker == 0) return;
    int idx = blockIdx.x * 256 + threadIdx.x;
    if (idx > 0 && idx < 64000) outf[idx] = 0.0f;
    if (idx == 0) outf[0] = (float)marker;
}

// ------------------------------------------------------------------ launch
extern "C" void kernel_launch(void* const* d_in, const int* in_sizes, int n_in,
                              void* d_out, int out_size, void* d_ws, size_t ws_size,
                              hipStream_t stream) {
    const float* img     = (const float*)d_in[0];
    const float* patch_w = (const float*)d_in[1];
    const float* patch_b = (const float*)d_in[2];
    const float* pos_emb = (const float*)d_in[3];
    const float* cls_tok = (const float*)d_in[4];
    const float* ln1_g   = (const float*)d_in[5];
    const float* ln1_b   = (const float*)d_in[6];
    const float* qkv_w   = (const float*)d_in[7];
    const float* scale   = (const float*)d_in[8];
    const float* out_w   = (const float*)d_in[9];
    const float* out_b   = (const float*)d_in[10];
    const float* ln2_g   = (const float*)d_in[11];
    const float* ln2_b   = (const float*)d_in[12];
    const float* ff_w1   = (const float*)d_in[13];
    const float* ff_b1   = (const float*)d_in[14];
    const float* ff_w2   = (const float*)d_in[15];
    const float* ff_b2   = (const float*)d_in[16];
    const float* lnf_g   = (const float*)d_in[17];
    const float* lnf_b   = (const float*)d_in[18];
    const float* head_w  = (const float*)d_in[19];
    const float* head_b  = (const float*)d_in[20];

    // Workspace layout (NEED = 58,146,816 B ~ 55.5 MB; proven to fit):
    const size_t NEED = 58146816;
    char* ws = (char*)d_ws;
    float* buf_x   = (float*)ws;
    bf16*  buf_hb  = (bf16*)(ws + 19365888);
    bf16*  buf_cd  = (bf16*)(ws + 29048832);
    bf16*  meanimg = (bf16*)(ws + 29048832 + 22478848);
    bf16*  buf_cls = (bf16*)(ws + 58097664);

    if (ws_size < NEED) {
        diag_kernel<<<250, 256, 0, stream>>>((const float*)d_out, (float*)d_out,
                                             1024 + (int)(ws_size >> 20), 0);
        return;
    }

    // patch embed pipeline (patch matrix in two 6272-row chunks)
    mean_kernel<<<(B_ * 50176 + 255) / 256, 256, 0, stream>>>(img, meanimg);
    for (int c = 0; c < 2; c++) {
        int bp0 = c * 6272;
        patches_kernel<<<6272, 256, 0, stream>>>(img, meanimg, buf_cd, bp0);
        mgemm_kernel<0, bf16><<<dim3(DIM_ / 64, 49), 256, 0, stream>>>(
            buf_cd, patch_w, patch_b, nullptr, buf_hb + (size_t)bp0 * DIM_, 6272, DIM_, PD_);
    }
    addpos_kernel<<<(B_ * N_ * DIM_ + 255) / 256, 256, 0, stream>>>(buf_hb, cls_tok, pos_emb, buf_x);

    const int ROWS = B_ * N_;  // 12608
    const int GY = (ROWS + 127) / 128;  // 99
    for (int i = 0; i < DEPTH_; i++) {
        ln_kernel<<<ROWS / 4, 256, 0, stream>>>(buf_x, DIM_, ln1_g + i * DIM_,
                                                ln1_b + i * DIM_, buf_hb, ROWS);
        mgemm_kernel<0, bf16><<<dim3((3 * INNER_) / 64, GY), 256, 0, stream>>>(
            buf_hb, qkv_w + (size_t)i * 3 * INNER_ * DIM_, nullptr, nullptr, buf_cd,
            ROWS, 3 * INNER_, DIM_);
        attn_mfma_kernel<<<dim3(B_, H_), 256, 0, stream>>>(buf_cd, scale + i * H_, buf_hb);
        mgemm_kernel<1, float><<<dim3(DIM_ / 64, GY), 256, 0, stream>>>(
            buf_hb, out_w + (size_t)i * DIM_ * INNER_, out_b + i * DIM_, buf_x, buf_x,
            ROWS, DIM_, INNER_);
        ln_kernel<<<ROWS / 4, 256, 0, stream>>>(buf_x, DIM_, ln2_g + i * DIM_,
                                                ln2_b + i * DIM_, buf_hb, ROWS);
        // FF in two row-chunks (6336 + 6272) to keep ff-mid within buf_cd
        int base = 0;
        for (int c = 0; c < 2; c++) {
            int mrows = (c == 0) ? 6336 : 6272;
            int gy = (mrows + 127) / 128;
            mgemm_kernel<2, bf16><<<dim3(MLP_ / 64, gy), 256, 0, stream>>>(
                buf_hb + (size_t)base * DIM_, ff_w1 + (size_t)i * MLP_ * DIM_,
                ff_b1 + i * MLP_, nullptr, buf_cd, mrows, MLP_, DIM_);
            mgemm_kernel<1, float><<<dim3(DIM_ / 64, gy), 256, 0, stream>>>(
                buf_cd, ff_w2 + (size_t)i * DIM_ * MLP_, ff_b2 + i * DIM_,
                buf_x + (size_t)base * DIM_, buf_x + (size_t)base * DIM_, mrows, DIM_, MLP_);
            base += mrows;
        }
    }

    ln_kernel<<<B_ / 4, 256, 0, stream>>>(buf_x, (long)N_ * DIM_, lnf_g, lnf_b, buf_cls, B_);
    gemm_kernel<0, float><<<dim3((NCLS_ + 63) / 64, 1), 256, 0, stream>>>(
        buf_cls, head_w, head_b, nullptr, (float*)d_out, B_, NCLS_, DIM_);

    diag_kernel<<<250, 256, 0, stream>>>(buf_x, (float*)d_out, 0, 1);
}

// Round 8
// 3127.042 us; speedup vs baseline: 5.1778x; 1.0239x over previous
//
#include <hip/hip_runtime.h>
#include <hip/hip_bf16.h>

// Model constants
#define B_ 64
#define IMG_ 224
#define P_ 16
#define G_ 14
#define NP_ 196
#define N_ 197
#define DIM_ 384
#define DEPTH_ 12
#define H_ 12
#define DH_ 32
#define INNER_ 384
#define MLP_ 1536
#define NCLS_ 1000
#define PD_ 1792
#define EPS_ 1e-5f

typedef __hip_bfloat16 bf16;
using bf16x8 = __attribute__((ext_vector_type(8))) short;   // 8 bf16 (4 VGPRs)
using f32x4  = __attribute__((ext_vector_type(4))) float;   // MFMA acc

typedef __attribute__((address_space(1))) const void gas_void;
typedef __attribute__((address_space(3))) void las_void;

__device__ __forceinline__ float b2f(bf16 x) { return __bfloat162float(x); }
__device__ __forceinline__ bf16 f2b(float x) { return __float2bfloat16(x); }
// raw RNE f32->bf16 (bit-level)
__device__ __forceinline__ short f2b_raw(float f) {
    unsigned x = __float_as_uint(f);
    unsigned r = (x + 0x7FFFu + ((x >> 16) & 1u)) >> 16;
    return (short)r;
}

// ---------------------------------------------------------------- weight f32->bf16
__global__ __launch_bounds__(256) void wconv_kernel(const float* __restrict__ src,
                                                    bf16* __restrict__ dst, int n4) {
    int i = blockIdx.x * 256 + threadIdx.x;
    if (i >= n4) return;
    float4 v = ((const float4*)src)[i];
    short4 o;
    o.x = f2b_raw(v.x); o.y = f2b_raw(v.y);
    o.z = f2b_raw(v.z); o.w = f2b_raw(v.w);
    ((short4*)dst)[i] = o;
}

// ---------------------------------------------------------------- mean image (bf16)
__global__ __launch_bounds__(256) void mean_kernel(const float* __restrict__ img,
                                                   bf16* __restrict__ meanimg) {
    int idx = blockIdx.x * 256 + threadIdx.x;
    if (idx >= B_ * 50176) return;
    int b = idx / 50176;
    int yx = idx - b * 50176;
    const float* p = img + (size_t)b * 3 * 50176 + yx;
    meanimg[idx] = f2b((p[0] + p[50176] + p[100352]) * (1.0f / 3.0f));
}

// ------------------------------------------------------------- patch matrix (chunk)
__global__ __launch_bounds__(256) void patches_kernel(const float* __restrict__ img,
                                                      const bf16* __restrict__ meanimg,
                                                      bf16* __restrict__ patches, int bp0) {
    int idx = blockIdx.x * 256 + threadIdx.x;
    if (idx >= 6272 * 256) return;
    int pix = idx & 255;
    int px = pix & 15, py = pix >> 4;
    int lbp = idx >> 8;
    int bp = bp0 + lbp;
    int p = bp % NP_;
    int b = bp / NP_;
    int gy = p / G_, gx = p - gy * G_;
    int y = gy * P_ + py, x = gx * P_ + px;
    const float* ib = img + (size_t)b * 3 * 50176 + y * 224 + x;
    bf16* out = patches + (size_t)lbp * PD_ + pix * 7;
    out[0] = f2b(ib[0]);
    out[1] = f2b(ib[50176]);
    out[2] = f2b(ib[100352]);
    const bf16* mb = meanimg + (size_t)b * 50176;
    out[3] = (x >= 8)  ? mb[y * 224 + x - 8]   : f2b(0.0f);   // l2
    out[4] = (x < 216) ? mb[y * 224 + x + 8]   : f2b(0.0f);   // r2
    out[5] = (y >= 8)  ? mb[(y - 8) * 224 + x] : f2b(0.0f);   // t2
    out[6] = (y < 216) ? mb[(y + 8) * 224 + x] : f2b(0.0f);   // b2
}

// --------------------------------------------------- cls + pos_emb assembly
__global__ __launch_bounds__(256) void addpos_kernel(const bf16* __restrict__ pe,
                                                     const float* __restrict__ cls_tok,
                                                     const float* __restrict__ pos_emb,
                                                     float* __restrict__ x) {
    int idx = blockIdx.x * 256 + threadIdx.x;
    if (idx >= B_ * N_ * DIM_) return;
    int c = idx % DIM_;
    int r = idx / DIM_;
    int t = r % N_;
    int b = r / N_;
    float v = (t == 0) ? cls_tok[c]
                       : b2f(pe[((size_t)(b * NP_ + t - 1)) * DIM_ + c]);
    x[idx] = v + pos_emb[t * DIM_ + c];
}

// ------------------------------------------------------------------ layernorm
__global__ __launch_bounds__(256) void ln_kernel(const float* __restrict__ in,
                                                 long in_stride,
                                                 const float* __restrict__ g,
                                                 const float* __restrict__ bb,
                                                 bf16* __restrict__ out, int rows) {
    int wave = threadIdx.x >> 6;
    int lane = threadIdx.x & 63;
    int row = blockIdx.x * 4 + wave;
    if (row >= rows) return;
    const float* p = in + (size_t)row * in_stride;
    float v[6];
    float s = 0.0f, s2 = 0.0f;
#pragma unroll
    for (int i = 0; i < 6; i++) {
        v[i] = p[lane + 64 * i];
        s += v[i];
        s2 += v[i] * v[i];
    }
#pragma unroll
    for (int m = 32; m >= 1; m >>= 1) {
        s += __shfl_xor(s, m);
        s2 += __shfl_xor(s2, m);
    }
    float mu = s * (1.0f / 384.0f);
    float var = s2 * (1.0f / 384.0f) - mu * mu;
    var = fmaxf(var, 0.0f);
    float inv = rsqrtf(var + EPS_);
    bf16* q = out + (size_t)row * DIM_;
#pragma unroll
    for (int i = 0; i < 6; i++) {
        int c = lane + 64 * i;
        q[c] = f2b((v[i] - mu) * inv * g[c] + bb[c]);
    }
}

// ------------------------------------------------------------------ MFMA GEMM v2 (m97-style)
// C[M,N] = A[M,K] @ W[N,K]^T, both bf16. Tile BM=128 BN=128 BK=32; 4 waves 2x2,
// wave microtile 64x64 (16 MFMA : 8 ds_read_b128). Staging via global_load_lds w16.
// MODE 0: bias. 1: bias+res(f32). 2: bias+exact GELU. N % 128 == 0 required.
template <int MODE, typename OutT>
__global__ __launch_bounds__(256) void mgemm2_kernel(const bf16* __restrict__ A,
                                                     const bf16* __restrict__ W,
                                                     const float* __restrict__ bias,
                                                     const float* __restrict__ res,
                                                     OutT* __restrict__ C,
                                                     int M, int N, int K) {
    __shared__ __align__(16) short lds_a[128 * 32];   // 8 KB
    __shared__ __align__(16) short lds_b[128 * 32];   // 8 KB
    int tid = threadIdx.x;
    int wv = tid >> 6, lane = tid & 63;
    int ml = lane & 15, quad = lane >> 4;
    int rowBase = blockIdx.y * 128, colBase = blockIdx.x * 128;

    // staging: wave wv pass p covers rows [p*64 + wv*16, +16); lane -> (row, kchunk)
    int srow = wv * 16 + (lane >> 2);
    int kcol = (lane & 3) * 8;
    int ar0 = rowBase + srow;       if (ar0 >= M) ar0 = M - 1;
    int ar1 = rowBase + 64 + srow;  if (ar1 >= M) ar1 = M - 1;
    const bf16* a0 = A + (size_t)ar0 * K + kcol;
    const bf16* a1 = A + (size_t)ar1 * K + kcol;
    const bf16* b0 = W + (size_t)(colBase + srow) * K + kcol;
    const bf16* b1 = W + (size_t)(colBase + 64 + srow) * K + kcol;
    short* la0 = lds_a + (wv * 16) * 32;        // wave-uniform LDS bases
    short* la1 = lds_a + (64 + wv * 16) * 32;
    short* lb0 = lds_b + (wv * 16) * 32;
    short* lb1 = lds_b + (64 + wv * 16) * 32;

    int wr = (wv >> 1) * 64, wc = (wv & 1) * 64;
    f32x4 acc[4][4] = {};

    for (int k0 = 0; k0 < K; k0 += 32) {
        __syncthreads();   // previous iteration's readers done
        __builtin_amdgcn_global_load_lds((gas_void*)(a0 + k0), (las_void*)la0, 16, 0, 0);
        __builtin_amdgcn_global_load_lds((gas_void*)(a1 + k0), (las_void*)la1, 16, 0, 0);
        __builtin_amdgcn_global_load_lds((gas_void*)(b0 + k0), (las_void*)lb0, 16, 0, 0);
        __builtin_amdgcn_global_load_lds((gas_void*)(b1 + k0), (las_void*)lb1, 16, 0, 0);
        __syncthreads();   // vmcnt drained -> LDS visible
        bf16x8 af[4], bfr[4];
#pragma unroll
        for (int rg = 0; rg < 4; rg++)
            af[rg] = *(const bf16x8*)(lds_a + (wr + rg * 16 + ml) * 32 + quad * 8);
#pragma unroll
        for (int cg = 0; cg < 4; cg++)
            bfr[cg] = *(const bf16x8*)(lds_b + (wc + cg * 16 + ml) * 32 + quad * 8);
#pragma unroll
        for (int rg = 0; rg < 4; rg++)
#pragma unroll
            for (int cg = 0; cg < 4; cg++)
                acc[rg][cg] = __builtin_amdgcn_mfma_f32_16x16x32_bf16(af[rg], bfr[cg], acc[rg][cg], 0, 0, 0);
    }

    float bval[4];
#pragma unroll
    for (int cg = 0; cg < 4; cg++)
        bval[cg] = bias ? bias[colBase + wc + cg * 16 + ml] : 0.0f;

#pragma unroll
    for (int rg = 0; rg < 4; rg++) {
#pragma unroll
        for (int reg = 0; reg < 4; reg++) {
            int r = rowBase + wr + rg * 16 + quad * 4 + reg;
            if (r >= M) continue;
            size_t ro = (size_t)r * N;
#pragma unroll
            for (int cg = 0; cg < 4; cg++) {
                int c = colBase + wc + cg * 16 + ml;
                float v = acc[rg][cg][reg] + bval[cg];
                if constexpr (MODE == 1) v += res[ro + c];
                if constexpr (MODE == 2) v = 0.5f * v * (1.0f + erff(v * 0.70710678118f));
                C[ro + c] = (OutT)v;
            }
        }
    }
}

// ------------------------------------------------------------------ MFMA GEMM v1 (fallback, W f32)
template <int MODE, typename OutT>
__global__ __launch_bounds__(256) void mgemm_kernel(const bf16* __restrict__ A,
                                                    const float* __restrict__ W,
                                                    const float* __restrict__ bias,
                                                    const float* __restrict__ res,
                                                    OutT* __restrict__ C,
                                                    int M, int N, int K) {
    __shared__ __align__(16) short lds_a[128 * 32];
    __shared__ __align__(16) short lds_b[64 * 32];
    int tid = threadIdx.x;
    int rowBase = blockIdx.y * 128;
    int colBase = blockIdx.x * 64;
    int w = tid >> 6, lane = tid & 63;
    int ml = lane & 15, kseg = lane >> 4;

    int ar = tid >> 1;
    int ah = (tid & 1) * 16;
    int agr = rowBase + ar;
    if (agr > M - 1) agr = M - 1;
    const float4* asrc_base = (const float4*)(A + (size_t)agr * K + ah);
    int br = tid >> 2;
    int bs = (tid & 3) * 8;
    const float4* wsrc_base = (const float4*)(W + (size_t)(colBase + br) * K + bs);

    f32x4 acc[2][4] = {};

    for (int k0 = 0; k0 < K; k0 += 32) {
        const float4* asrc = (const float4*)((const bf16*)asrc_base + k0);
        float4 av0 = asrc[0];
        float4 av1 = asrc[1];
        const float4* wsrc = (const float4*)((const float*)wsrc_base + k0);
        float4 w0 = wsrc[0];
        float4 w1 = wsrc[1];
        bf16x8 wb;
        wb[0] = f2b_raw(w0.x); wb[1] = f2b_raw(w0.y);
        wb[2] = f2b_raw(w0.z); wb[3] = f2b_raw(w0.w);
        wb[4] = f2b_raw(w1.x); wb[5] = f2b_raw(w1.y);
        wb[6] = f2b_raw(w1.z); wb[7] = f2b_raw(w1.w);
        __syncthreads();
        *(float4*)(lds_a + ar * 32 + ah) = av0;
        *(float4*)(lds_a + ar * 32 + ah + 8) = av1;
        *(bf16x8*)(lds_b + br * 32 + bs) = wb;
        __syncthreads();
        bf16x8 af0 = *(const bf16x8*)(lds_a + (w * 32 + ml) * 32 + kseg * 8);
        bf16x8 af1 = *(const bf16x8*)(lds_a + (w * 32 + 16 + ml) * 32 + kseg * 8);
#pragma unroll
        for (int ct = 0; ct < 4; ct++) {
            bf16x8 bf_ = *(const bf16x8*)(lds_b + (ct * 16 + ml) * 32 + kseg * 8);
            acc[0][ct] = __builtin_amdgcn_mfma_f32_16x16x32_bf16(af0, bf_, acc[0][ct], 0, 0, 0);
            acc[1][ct] = __builtin_amdgcn_mfma_f32_16x16x32_bf16(af1, bf_, acc[1][ct], 0, 0, 0);
        }
    }

    float bval[4];
#pragma unroll
    for (int ct = 0; ct < 4; ct++)
        bval[ct] = bias ? bias[colBase + ct * 16 + ml] : 0.0f;

#pragma unroll
    for (int rt = 0; rt < 2; rt++) {
#pragma unroll
        for (int reg = 0; reg < 4; reg++) {
            int r = rowBase + w * 32 + rt * 16 + kseg * 4 + reg;
            if (r >= M) continue;
            size_t ro = (size_t)r * N;
#pragma unroll
            for (int ct = 0; ct < 4; ct++) {
                int c = colBase + ct * 16 + ml;
                float v = acc[rt][ct][reg] + bval[ct];
                if constexpr (MODE == 1) v += res[ro + c];
                if constexpr (MODE == 2) v = 0.5f * v * (1.0f + erff(v * 0.70710678118f));
                C[ro + c] = (OutT)v;
            }
        }
    }
}

// ------------------------------------------------------------------ VALU GEMM (head only)
template <int MODE, typename OutT>
__global__ __launch_bounds__(256) void gemm_kernel(const bf16* __restrict__ A,
                                                   const float* __restrict__ W,
                                                   const float* __restrict__ bias,
                                                   const float* res, OutT* C,
                                                   int M, int N, int K) {
    __shared__ float As[32][65];
    __shared__ float Ws[32][65];
    int tid = threadIdx.x;
    int rowBase = blockIdx.y * 64;
    int colBase = blockIdx.x * 64;
    int lr = tid >> 2;
    int lk = (tid & 3) * 8;
    int tx = tid & 15, ty = tid >> 4;
    float acc[4][4] = {};
    for (int k0 = 0; k0 < K; k0 += 32) {
        int gr = rowBase + lr;
        const bf16* asrc = A + (size_t)gr * K + k0 + lk;
        bool aok = (gr < M);
#pragma unroll
        for (int e = 0; e < 8; e++) As[lk + e][lr] = aok ? b2f(asrc[e]) : 0.0f;
        int gc = colBase + lr;
        const float* wsrc = W + (size_t)gc * K + k0 + lk;
        bool wok = (gc < N);
#pragma unroll
        for (int e = 0; e < 8; e++) Ws[lk + e][lr] = wok ? wsrc[e] : 0.0f;
        __syncthreads();
#pragma unroll
        for (int kk = 0; kk < 32; kk++) {
            float a[4], b[4];
#pragma unroll
            for (int i = 0; i < 4; i++) a[i] = As[kk][ty * 4 + i];
#pragma unroll
            for (int j = 0; j < 4; j++) b[j] = Ws[kk][tx * 4 + j];
#pragma unroll
            for (int i = 0; i < 4; i++)
#pragma unroll
                for (int j = 0; j < 4; j++) acc[i][j] += a[i] * b[j];
        }
        __syncthreads();
    }
#pragma unroll
    for (int i = 0; i < 4; i++) {
        int r = rowBase + ty * 4 + i;
        if (r >= M) continue;
#pragma unroll
        for (int j = 0; j < 4; j++) {
            int c = colBase + tx * 4 + j;
            if (c >= N) continue;
            float v = acc[i][j];
            if (bias) v += bias[c];
            if constexpr (MODE == 1) v += res[(size_t)r * N + c];
            if constexpr (MODE == 2) v = 0.5f * v * (1.0f + erff(v * 0.70710678118f));
            C[(size_t)r * N + c] = (OutT)v;
        }
    }
}

// ------------------------------------------------------------------ MFMA attention
#define AKR 208
#define VTS 232
#define PSS 232
__global__ __launch_bounds__(256) void attn_mfma_kernel(const bf16* __restrict__ qkv,
                                                        const float* __restrict__ scale,
                                                        bf16* __restrict__ o) {
    __shared__ __align__(16) short Ks[AKR * 32];
    __shared__ __align__(16) short Vt[32 * VTS];
    __shared__ __align__(16) short Ps[4][16 * PSS];
    int b = blockIdx.x, h = blockIdx.y;
    int tid = threadIdx.x;
    int w = tid >> 6, lane = tid & 63;
    int ml = lane & 15, quad = lane >> 4;

    for (int i = tid; i < 32 * VTS / 2; i += 256) ((int*)Vt)[i] = 0;
    for (int e = lane; e < 16 * 16; e += 64) {
        int r = e >> 4, c = e & 15;
        Ps[w][r * PSS + 208 + c] = 0;
    }
    __syncthreads();
    for (int e = tid; e < AKR * 4; e += 256) {
        int row = e >> 2, seg = e & 3;
        float4 v = {0.0f, 0.0f, 0.0f, 0.0f};
        if (row < N_)
            v = *(const float4*)(qkv + (size_t)(b * N_ + row) * (3 * INNER_) + INNER_ + h * DH_ + seg * 8);
        *(float4*)(Ks + row * 32 + seg * 8) = v;
    }
    for (int e = tid; e < N_ * 32; e += 256) {
        int j = e >> 5, d = e & 31;
        Vt[d * VTS + j] = *(const short*)(qkv + (size_t)(b * N_ + j) * (3 * INNER_) + 2 * INNER_ + h * DH_ + d);
    }
    __syncthreads();

    float sc = scale[h];
    for (int qt = w; qt < 13; qt += 4) {
        int q0 = qt * 16;
        int qrow = q0 + ml;
        if (qrow > N_ - 1) qrow = N_ - 1;
        bf16x8 aq = *(const bf16x8*)(qkv + (size_t)(b * N_ + qrow) * (3 * INNER_) + h * DH_ + quad * 8);
        f32x4 accs[13];
#pragma unroll
        for (int kt = 0; kt < 13; kt++) {
            bf16x8 bk = *(const bf16x8*)(Ks + (kt * 16 + ml) * 32 + quad * 8);
            f32x4 z = {0.0f, 0.0f, 0.0f, 0.0f};
            accs[kt] = __builtin_amdgcn_mfma_f32_16x16x32_bf16(aq, bk, z, 0, 0, 0);
        }
        float rmax[4] = {-1e30f, -1e30f, -1e30f, -1e30f};
#pragma unroll
        for (int kt = 0; kt < 13; kt++) {
            int key = kt * 16 + ml;
#pragma unroll
            for (int reg = 0; reg < 4; reg++) {
                int qg = q0 + quad * 4 + reg;
                bool valid = (key < N_) && (key != qg);
                float s = valid ? accs[kt][reg] * sc : -1e30f;
                accs[kt][reg] = s;
                rmax[reg] = fmaxf(rmax[reg], s);
            }
        }
#pragma unroll
        for (int m = 1; m <= 8; m <<= 1)
#pragma unroll
            for (int reg = 0; reg < 4; reg++)
                rmax[reg] = fmaxf(rmax[reg], __shfl_xor(rmax[reg], m));
        float rsum[4] = {0.0f, 0.0f, 0.0f, 0.0f};
#pragma unroll
        for (int kt = 0; kt < 13; kt++) {
#pragma unroll
            for (int reg = 0; reg < 4; reg++) {
                float wgt = __expf(accs[kt][reg] - rmax[reg]);
                accs[kt][reg] = wgt;
                rsum[reg] += wgt;
            }
        }
#pragma unroll
        for (int m = 1; m <= 8; m <<= 1)
#pragma unroll
            for (int reg = 0; reg < 4; reg++)
                rsum[reg] += __shfl_xor(rsum[reg], m);
#pragma unroll
        for (int kt = 0; kt < 13; kt++)
#pragma unroll
            for (int reg = 0; reg < 4; reg++)
                Ps[w][(quad * 4 + reg) * PSS + kt * 16 + ml] = f2b_raw(accs[kt][reg]);
        f32x4 acco[2] = {{0.0f, 0.0f, 0.0f, 0.0f}, {0.0f, 0.0f, 0.0f, 0.0f}};
#pragma unroll
        for (int kc = 0; kc < 7; kc++) {
            bf16x8 ap = *(const bf16x8*)(Ps[w] + ml * PSS + kc * 32 + quad * 8);
#pragma unroll
            for (int nt = 0; nt < 2; nt++) {
                bf16x8 bv = *(const bf16x8*)(Vt + (nt * 16 + ml) * VTS + kc * 32 + quad * 8);
                acco[nt] = __builtin_amdgcn_mfma_f32_16x16x32_bf16(ap, bv, acco[nt], 0, 0, 0);
            }
        }
#pragma unroll
        for (int reg = 0; reg < 4; reg++) {
            int qg = q0 + quad * 4 + reg;
            if (qg >= N_) continue;
            float inv = 1.0f / rsum[reg];
#pragma unroll
            for (int nt = 0; nt < 2; nt++)
                o[(size_t)(b * N_ + qg) * INNER_ + h * DH_ + nt * 16 + ml] = f2b(acco[nt][reg] * inv);
        }
    }
}

// ------------------------------------------------------------------ diagnostics (f32 out)
__global__ __launch_bounds__(256) void diag_kernel(const float* __restrict__ bufx,
                                                   float* __restrict__ outf,
                                                   int base_marker, int ran) {
    __shared__ int bad;
    if (threadIdx.x == 0) bad = 0;
    __syncthreads();
    if (ran) {
        for (int i = threadIdx.x; i < 4096; i += 256) {
            float v = bufx[i];
            if (!(fabsf(v) < 1e30f)) bad = 1;
        }
    }
    __syncthreads();
    int marker = base_marker + (bad ? 512 : 0);
    if (marker == 0) return;
    int idx = blockIdx.x * 256 + threadIdx.x;
    if (idx > 0 && idx < 64000) outf[idx] = 0.0f;
    if (idx == 0) outf[0] = (float)marker;
}

// ------------------------------------------------------------------ launch
extern "C" void kernel_launch(void* const* d_in, const int* in_sizes, int n_in,
                              void* d_out, int out_size, void* d_ws, size_t ws_size,
                              hipStream_t stream) {
    const float* img     = (const float*)d_in[0];
    const float* patch_w = (const float*)d_in[1];
    const float* patch_b = (const float*)d_in[2];
    const float* pos_emb = (const float*)d_in[3];
    const float* cls_tok = (const float*)d_in[4];
    const float* ln1_g   = (const float*)d_in[5];
    const float* ln1_b   = (const float*)d_in[6];
    const float* qkv_w   = (const float*)d_in[7];
    const float* scale   = (const float*)d_in[8];
    const float* out_w   = (const float*)d_in[9];
    const float* out_b   = (const float*)d_in[10];
    const float* ln2_g   = (const float*)d_in[11];
    const float* ln2_b   = (const float*)d_in[12];
    const float* ff_w1   = (const float*)d_in[13];
    const float* ff_b1   = (const float*)d_in[14];
    const float* ff_w2   = (const float*)d_in[15];
    const float* ff_b2   = (const float*)d_in[16];
    const float* lnf_g   = (const float*)d_in[17];
    const float* lnf_b   = (const float*)d_in[18];
    const float* head_w  = (const float*)d_in[19];
    const float* head_b  = (const float*)d_in[20];

    // Base workspace (proven to fit): 58,146,816 B
    //  buf_x  f32  @ 0          19,365,888
    //  buf_hb bf16 @ 19,365,888  9,682,944
    //  buf_cd bf16 @ 29,048,832 29,048,832  (qkv | patches+meanimg | ffmid)
    //  buf_cls     @ 58,097,664     49,152
    // Fast-path extra (bf16 weights): +43,843,584 -> NEED_FAST = 101,990,400
    const size_t NEED = 58146816;
    const size_t NEED_FAST = 101990400;
    char* ws = (char*)d_ws;
    float* buf_x   = (float*)ws;
    bf16*  buf_hb  = (bf16*)(ws + 19365888);
    bf16*  buf_cd  = (bf16*)(ws + 29048832);
    bf16*  meanimg = (bf16*)(ws + 29048832 + 22478848);
    bf16*  buf_cls = (bf16*)(ws + 58097664);
    bf16*  wb_patch = (bf16*)(ws + 58146816);
    bf16*  wb_qkv   = (bf16*)(ws + 59523072);
    bf16*  wb_out   = (bf16*)(ws + 70139904);
    bf16*  wb_ff1   = (bf16*)(ws + 73678848);
    bf16*  wb_ff2   = (bf16*)(ws + 87834624);

    if (ws_size < NEED) {
        diag_kernel<<<250, 256, 0, stream>>>((const float*)d_out, (float*)d_out,
                                             1024 + (int)(ws_size >> 20), 0);
        return;
    }
    const bool fast = (ws_size >= NEED_FAST);

    const int ROWS = B_ * N_;  // 12608
    const int GY = (ROWS + 127) / 128;  // 99

    if (fast) {
        // one-time (per launch) weight conversion f32 -> bf16
        wconv_kernel<<<(688128 / 4 + 255) / 256, 256, 0, stream>>>(patch_w, wb_patch, 688128 / 4);
        wconv_kernel<<<(5308416 / 4 + 255) / 256, 256, 0, stream>>>(qkv_w, wb_qkv, 5308416 / 4);
        wconv_kernel<<<(1769472 / 4 + 255) / 256, 256, 0, stream>>>(out_w, wb_out, 1769472 / 4);
        wconv_kernel<<<(7077888 / 4 + 255) / 256, 256, 0, stream>>>(ff_w1, wb_ff1, 7077888 / 4);
        wconv_kernel<<<(7077888 / 4 + 255) / 256, 256, 0, stream>>>(ff_w2, wb_ff2, 7077888 / 4);

        mean_kernel<<<(B_ * 50176 + 255) / 256, 256, 0, stream>>>(img, meanimg);
        for (int c = 0; c < 2; c++) {
            int bp0 = c * 6272;
            patches_kernel<<<6272, 256, 0, stream>>>(img, meanimg, buf_cd, bp0);
            mgemm2_kernel<0, bf16><<<dim3(3, 49), 256, 0, stream>>>(
                buf_cd, wb_patch, patch_b, nullptr, buf_hb + (size_t)bp0 * DIM_, 6272, DIM_, PD_);
        }
        addpos_kernel<<<(B_ * N_ * DIM_ + 255) / 256, 256, 0, stream>>>(buf_hb, cls_tok, pos_emb, buf_x);

        for (int i = 0; i < DEPTH_; i++) {
            ln_kernel<<<ROWS / 4, 256, 0, stream>>>(buf_x, DIM_, ln1_g + i * DIM_,
                                                    ln1_b + i * DIM_, buf_hb, ROWS);
            mgemm2_kernel<0, bf16><<<dim3(9, GY), 256, 0, stream>>>(
                buf_hb, wb_qkv + (size_t)i * 3 * INNER_ * DIM_, nullptr, nullptr, buf_cd,
                ROWS, 3 * INNER_, DIM_);
            attn_mfma_kernel<<<dim3(B_, H_), 256, 0, stream>>>(buf_cd, scale + i * H_, buf_hb);
            mgemm2_kernel<1, float><<<dim3(3, GY), 256, 0, stream>>>(
                buf_hb, wb_out + (size_t)i * DIM_ * INNER_, out_b + i * DIM_, buf_x, buf_x,
                ROWS, DIM_, INNER_);
            ln_kernel<<<ROWS / 4, 256, 0, stream>>>(buf_x, DIM_, ln2_g + i * DIM_,
                                                    ln2_b + i * DIM_, buf_hb, ROWS);
            int base = 0;
            for (int c = 0; c < 2; c++) {
                int mrows = (c == 0) ? 6336 : 6272;
                int gy = (mrows + 127) / 128;
                mgemm2_kernel<2, bf16><<<dim3(12, gy), 256, 0, stream>>>(
                    buf_hb + (size_t)base * DIM_, wb_ff1 + (size_t)i * MLP_ * DIM_,
                    ff_b1 + i * MLP_, nullptr, buf_cd, mrows, MLP_, DIM_);
                mgemm2_kernel<1, float><<<dim3(3, gy), 256, 0, stream>>>(
                    buf_cd, wb_ff2 + (size_t)i * DIM_ * MLP_, ff_b2 + i * DIM_,
                    buf_x + (size_t)base * DIM_, buf_x + (size_t)base * DIM_, mrows, DIM_, MLP_);
                base += mrows;
            }
        }
    } else {
        // fallback: round-7 proven path (W f32 in-kernel convert)
        mean_kernel<<<(B_ * 50176 + 255) / 256, 256, 0, stream>>>(img, meanimg);
        for (int c = 0; c < 2; c++) {
            int bp0 = c * 6272;
            patches_kernel<<<6272, 256, 0, stream>>>(img, meanimg, buf_cd, bp0);
            mgemm_kernel<0, bf16><<<dim3(DIM_ / 64, 49), 256, 0, stream>>>(
                buf_cd, patch_w, patch_b, nullptr, buf_hb + (size_t)bp0 * DIM_, 6272, DIM_, PD_);
        }
        addpos_kernel<<<(B_ * N_ * DIM_ + 255) / 256, 256, 0, stream>>>(buf_hb, cls_tok, pos_emb, buf_x);

        for (int i = 0; i < DEPTH_; i++) {
            ln_kernel<<<ROWS / 4, 256, 0, stream>>>(buf_x, DIM_, ln1_g + i * DIM_,
                                                    ln1_b + i * DIM_, buf_hb, ROWS);
            mgemm_kernel<0, bf16><<<dim3((3 * INNER_) / 64, GY), 256, 0, stream>>>(
                buf_hb, qkv_w + (size_t)i * 3 * INNER_ * DIM_, nullptr, nullptr, buf_cd,
                ROWS, 3 * INNER_, DIM_);
            attn_mfma_kernel<<<dim3(B_, H_), 256, 0, stream>>>(buf_cd, scale + i * H_, buf_hb);
            mgemm_kernel<1, float><<<dim3(DIM_ / 64, GY), 256, 0, stream>>>(
                buf_hb, out_w + (size_t)i * DIM_ * INNER_, out_b + i * DIM_, buf_x, buf_x,
                ROWS, DIM_, INNER_);
            ln_kernel<<<ROWS / 4, 256, 0, stream>>>(buf_x, DIM_, ln2_g + i * DIM_,
                                                    ln2_b + i * DIM_, buf_hb, ROWS);
            int base = 0;
            for (int c = 0; c < 2; c++) {
                int mrows = (c == 0) ? 6336 : 6272;
                int gy = (mrows + 127) / 128;
                mgemm_kernel<2, bf16><<<dim3(MLP_ / 64, gy), 256, 0, stream>>>(
                    buf_hb + (size_t)base * DIM_, ff_w1 + (size_t)i * MLP_ * DIM_,
                    ff_b1 + i * MLP_, nullptr, buf_cd, mrows, MLP_, DIM_);
                mgemm_kernel<1, float><<<dim3(DIM_ / 64, gy), 256, 0, stream>>>(
                    buf_cd, ff_w2 + (size_t)i * DIM_ * MLP_, ff_b2 + i * DIM_,
                    buf_x + (size_t)base * DIM_, buf_x + (size_t)base * DIM_, mrows, DIM_, MLP_);
                base += mrows;
            }
        }
    }

    ln_kernel<<<B_ / 4, 256, 0, stream>>>(buf_x, (long)N_ * DIM_, lnf_g, lnf_b, buf_cls, B_);
    gemm_kernel<0, float><<<dim3((NCLS_ + 63) / 64, 1), 256, 0, stream>>>(
        buf_cls, head_w, head_b, nullptr, (float*)d_out, B_, NCLS_, DIM_);

    diag_kernel<<<250, 256, 0, stream>>>(buf_x, (float*)d_out, 0, 1);
}

// Round 9
// 2950.479 us; speedup vs baseline: 5.4876x; 1.0598x over previous
//
#include <hip/hip_runtime.h>
#include <hip/hip_bf16.h>

// Model constants
#define B_ 64
#define IMG_ 224
#define P_ 16
#define G_ 14
#define NP_ 196
#define N_ 197
#define DIM_ 384
#define DEPTH_ 12
#define H_ 12
#define DH_ 32
#define INNER_ 384
#define MLP_ 1536
#define NCLS_ 1000
#define PD_ 1792
#define EPS_ 1e-5f

typedef __hip_bfloat16 bf16;
using bf16x8 = __attribute__((ext_vector_type(8))) short;   // 8 bf16 (4 VGPRs)
using f32x4  = __attribute__((ext_vector_type(4))) float;   // MFMA acc

typedef __attribute__((address_space(1))) const void gas_void;
typedef __attribute__((address_space(3))) void las_void;

__device__ __forceinline__ float b2f(bf16 x) { return __bfloat162float(x); }
__device__ __forceinline__ bf16 f2b(float x) { return __float2bfloat16(x); }
// raw RNE f32->bf16 (bit-level)
__device__ __forceinline__ short f2b_raw(float f) {
    unsigned x = __float_as_uint(f);
    unsigned r = (x + 0x7FFFu + ((x >> 16) & 1u)) >> 16;
    return (short)r;
}
// raw workgroup barrier WITHOUT implicit vmcnt(0) drain (memory-clobber asm:
// compiler cannot move LDS/global ops across it, and inserts no waitcnt).
__device__ __forceinline__ void barrier_raw() {
    asm volatile("s_barrier" ::: "memory");
}
__device__ __forceinline__ void waitcnt_vm4() {
    asm volatile("s_waitcnt vmcnt(4)" ::: "memory");
}
__device__ __forceinline__ void waitcnt_vm0() {
    asm volatile("s_waitcnt vmcnt(0)" ::: "memory");
}

// ---------------------------------------------------------------- weight f32->bf16
__global__ __launch_bounds__(256) void wconv_kernel(const float* __restrict__ src,
                                                    bf16* __restrict__ dst, int n4) {
    int i = blockIdx.x * 256 + threadIdx.x;
    if (i >= n4) return;
    float4 v = ((const float4*)src)[i];
    short4 o;
    o.x = f2b_raw(v.x); o.y = f2b_raw(v.y);
    o.z = f2b_raw(v.z); o.w = f2b_raw(v.w);
    ((short4*)dst)[i] = o;
}

// ---------------------------------------------------------------- mean image (bf16)
__global__ __launch_bounds__(256) void mean_kernel(const float* __restrict__ img,
                                                   bf16* __restrict__ meanimg) {
    int idx = blockIdx.x * 256 + threadIdx.x;
    if (idx >= B_ * 50176) return;
    int b = idx / 50176;
    int yx = idx - b * 50176;
    const float* p = img + (size_t)b * 3 * 50176 + yx;
    meanimg[idx] = f2b((p[0] + p[50176] + p[100352]) * (1.0f / 3.0f));
}

// ------------------------------------------------------------- patch matrix (chunk)
__global__ __launch_bounds__(256) void patches_kernel(const float* __restrict__ img,
                                                      const bf16* __restrict__ meanimg,
                                                      bf16* __restrict__ patches, int bp0) {
    int idx = blockIdx.x * 256 + threadIdx.x;
    if (idx >= 6272 * 256) return;
    int pix = idx & 255;
    int px = pix & 15, py = pix >> 4;
    int lbp = idx >> 8;
    int bp = bp0 + lbp;
    int p = bp % NP_;
    int b = bp / NP_;
    int gy = p / G_, gx = p - gy * G_;
    int y = gy * P_ + py, x = gx * P_ + px;
    const float* ib = img + (size_t)b * 3 * 50176 + y * 224 + x;
    bf16* out = patches + (size_t)lbp * PD_ + pix * 7;
    out[0] = f2b(ib[0]);
    out[1] = f2b(ib[50176]);
    out[2] = f2b(ib[100352]);
    const bf16* mb = meanimg + (size_t)b * 50176;
    out[3] = (x >= 8)  ? mb[y * 224 + x - 8]   : f2b(0.0f);   // l2
    out[4] = (x < 216) ? mb[y * 224 + x + 8]   : f2b(0.0f);   // r2
    out[5] = (y >= 8)  ? mb[(y - 8) * 224 + x] : f2b(0.0f);   // t2
    out[6] = (y < 216) ? mb[(y + 8) * 224 + x] : f2b(0.0f);   // b2
}

// --------------------------------------------------- cls + pos_emb assembly
__global__ __launch_bounds__(256) void addpos_kernel(const bf16* __restrict__ pe,
                                                     const float* __restrict__ cls_tok,
                                                     const float* __restrict__ pos_emb,
                                                     float* __restrict__ x) {
    int idx = blockIdx.x * 256 + threadIdx.x;
    if (idx >= B_ * N_ * DIM_) return;
    int c = idx % DIM_;
    int r = idx / DIM_;
    int t = r % N_;
    int b = r / N_;
    float v = (t == 0) ? cls_tok[c]
                       : b2f(pe[((size_t)(b * NP_ + t - 1)) * DIM_ + c]);
    x[idx] = v + pos_emb[t * DIM_ + c];
}

// ------------------------------------------------------------------ layernorm
__global__ __launch_bounds__(256) void ln_kernel(const float* __restrict__ in,
                                                 long in_stride,
                                                 const float* __restrict__ g,
                                                 const float* __restrict__ bb,
                                                 bf16* __restrict__ out, int rows) {
    int wave = threadIdx.x >> 6;
    int lane = threadIdx.x & 63;
    int row = blockIdx.x * 4 + wave;
    if (row >= rows) return;
    const float* p = in + (size_t)row * in_stride;
    float v[6];
    float s = 0.0f, s2 = 0.0f;
#pragma unroll
    for (int i = 0; i < 6; i++) {
        v[i] = p[lane + 64 * i];
        s += v[i];
        s2 += v[i] * v[i];
    }
#pragma unroll
    for (int m = 32; m >= 1; m >>= 1) {
        s += __shfl_xor(s, m);
        s2 += __shfl_xor(s2, m);
    }
    float mu = s * (1.0f / 384.0f);
    float var = s2 * (1.0f / 384.0f) - mu * mu;
    var = fmaxf(var, 0.0f);
    float inv = rsqrtf(var + EPS_);
    bf16* q = out + (size_t)row * DIM_;
#pragma unroll
    for (int i = 0; i < 6; i++) {
        int c = lane + 64 * i;
        q[c] = f2b((v[i] - mu) * inv * g[c] + bb[c]);
    }
}

// ------------------------------------------------------------------ MFMA GEMM v3 (pipelined)
// C[M,N] = A[M,K] @ W[N,K]^T, both bf16. Tile BM=128 BN=128 BK=32; 4 waves 2x2,
// wave microtile 64x64. Double-buffered LDS; tile k+1 loads issued one iteration
// ahead via global_load_lds; raw s_barrier + explicit s_waitcnt vmcnt(4) so the
// prefetch stays in flight across the barrier (no vmcnt(0) drain).
// MODE 0: bias. 1: bias+res(f32). 2: bias+exact GELU. N % 128 == 0, K % 32 == 0, K>=64.
template <int MODE, typename OutT>
__global__ __launch_bounds__(256) void mgemm3_kernel(const bf16* __restrict__ A,
                                                     const bf16* __restrict__ W,
                                                     const float* __restrict__ bias,
                                                     const float* __restrict__ res,
                                                     OutT* __restrict__ C,
                                                     int M, int N, int K) {
    __shared__ __align__(16) short lds_a[2][128 * 32];   // 2 x 8 KB
    __shared__ __align__(16) short lds_b[2][128 * 32];   // 2 x 8 KB
    int tid = threadIdx.x;
    int wv = tid >> 6, lane = tid & 63;
    int ml = lane & 15, quad = lane >> 4;
    int rowBase = blockIdx.y * 128, colBase = blockIdx.x * 128;

    // staging: wave wv covers rows [wv*16,+16) and [64+wv*16,+16); lane -> (row,kchunk)
    int srow = wv * 16 + (lane >> 2);
    int kcol = (lane & 3) * 8;
    int ar0 = rowBase + srow;       if (ar0 >= M) ar0 = M - 1;
    int ar1 = rowBase + 64 + srow;  if (ar1 >= M) ar1 = M - 1;
    const bf16* a0 = A + (size_t)ar0 * K + kcol;
    const bf16* a1 = A + (size_t)ar1 * K + kcol;
    const bf16* b0 = W + (size_t)(colBase + srow) * K + kcol;
    const bf16* b1 = W + (size_t)(colBase + 64 + srow) * K + kcol;
    // wave-uniform LDS bases, per buffer
    short* laA[2]  = { lds_a[0] + (wv * 16) * 32,      lds_a[1] + (wv * 16) * 32 };
    short* laA2[2] = { lds_a[0] + (64 + wv * 16) * 32, lds_a[1] + (64 + wv * 16) * 32 };
    short* lbB[2]  = { lds_b[0] + (wv * 16) * 32,      lds_b[1] + (wv * 16) * 32 };
    short* lbB2[2] = { lds_b[0] + (64 + wv * 16) * 32, lds_b[1] + (64 + wv * 16) * 32 };

#define ISSUE_TILE(buf, k0)                                                                   \
    do {                                                                                      \
        __builtin_amdgcn_global_load_lds((gas_void*)(a0 + (k0)), (las_void*)laA[buf], 16, 0, 0);  \
        __builtin_amdgcn_global_load_lds((gas_void*)(a1 + (k0)), (las_void*)laA2[buf], 16, 0, 0); \
        __builtin_amdgcn_global_load_lds((gas_void*)(b0 + (k0)), (las_void*)lbB[buf], 16, 0, 0);  \
        __builtin_amdgcn_global_load_lds((gas_void*)(b1 + (k0)), (las_void*)lbB2[buf], 16, 0, 0); \
    } while (0)

    int wr = (wv >> 1) * 64, wc = (wv & 1) * 64;
    f32x4 acc[4][4] = {};
    int NK = K >> 5;

    ISSUE_TILE(0, 0);
    ISSUE_TILE(1, 32);

    for (int k = 0; k < NK; k++) {
        if (k + 1 < NK) waitcnt_vm4();   // tile k's 4 loads done; k+1's stay in flight
        else            waitcnt_vm0();
        barrier_raw();                   // all waves' tile-k LDS writes visible
        int cb = k & 1;
        bf16x8 af[4], bfr[4];
#pragma unroll
        for (int rg = 0; rg < 4; rg++)
            af[rg] = *(const bf16x8*)(lds_a[cb] + (wr + rg * 16 + ml) * 32 + quad * 8);
#pragma unroll
        for (int cg = 0; cg < 4; cg++)
            bfr[cg] = *(const bf16x8*)(lds_b[cb] + (wc + cg * 16 + ml) * 32 + quad * 8);
#pragma unroll
        for (int rg = 0; rg < 4; rg++)
#pragma unroll
            for (int cg = 0; cg < 4; cg++)
                acc[rg][cg] = __builtin_amdgcn_mfma_f32_16x16x32_bf16(af[rg], bfr[cg], acc[rg][cg], 0, 0, 0);
        barrier_raw();                   // all waves done reading buf cb
        if (k + 2 < NK) ISSUE_TILE(cb, (k + 2) * 32);
    }
#undef ISSUE_TILE

    float bval[4];
#pragma unroll
    for (int cg = 0; cg < 4; cg++)
        bval[cg] = bias ? bias[colBase + wc + cg * 16 + ml] : 0.0f;

#pragma unroll
    for (int rg = 0; rg < 4; rg++) {
#pragma unroll
        for (int reg = 0; reg < 4; reg++) {
            int r = rowBase + wr + rg * 16 + quad * 4 + reg;
            if (r >= M) continue;
            size_t ro = (size_t)r * N;
#pragma unroll
            for (int cg = 0; cg < 4; cg++) {
                int c = colBase + wc + cg * 16 + ml;
                float v = acc[rg][cg][reg] + bval[cg];
                if constexpr (MODE == 1) v += res[ro + c];
                if constexpr (MODE == 2) v = 0.5f * v * (1.0f + erff(v * 0.70710678118f));
                C[ro + c] = (OutT)v;
            }
        }
    }
}

// ------------------------------------------------------------------ MFMA GEMM v1 (fallback, W f32)
template <int MODE, typename OutT>
__global__ __launch_bounds__(256) void mgemm_kernel(const bf16* __restrict__ A,
                                                    const float* __restrict__ W,
                                                    const float* __restrict__ bias,
                                                    const float* __restrict__ res,
                                                    OutT* __restrict__ C,
                                                    int M, int N, int K) {
    __shared__ __align__(16) short lds_a[128 * 32];
    __shared__ __align__(16) short lds_b[64 * 32];
    int tid = threadIdx.x;
    int rowBase = blockIdx.y * 128;
    int colBase = blockIdx.x * 64;
    int w = tid >> 6, lane = tid & 63;
    int ml = lane & 15, kseg = lane >> 4;

    int ar = tid >> 1;
    int ah = (tid & 1) * 16;
    int agr = rowBase + ar;
    if (agr > M - 1) agr = M - 1;
    const float4* asrc_base = (const float4*)(A + (size_t)agr * K + ah);
    int br = tid >> 2;
    int bs = (tid & 3) * 8;
    const float4* wsrc_base = (const float4*)(W + (size_t)(colBase + br) * K + bs);

    f32x4 acc[2][4] = {};

    for (int k0 = 0; k0 < K; k0 += 32) {
        const float4* asrc = (const float4*)((const bf16*)asrc_base + k0);
        float4 av0 = asrc[0];
        float4 av1 = asrc[1];
        const float4* wsrc = (const float4*)((const float*)wsrc_base + k0);
        float4 w0 = wsrc[0];
        float4 w1 = wsrc[1];
        bf16x8 wb;
        wb[0] = f2b_raw(w0.x); wb[1] = f2b_raw(w0.y);
        wb[2] = f2b_raw(w0.z); wb[3] = f2b_raw(w0.w);
        wb[4] = f2b_raw(w1.x); wb[5] = f2b_raw(w1.y);
        wb[6] = f2b_raw(w1.z); wb[7] = f2b_raw(w1.w);
        __syncthreads();
        *(float4*)(lds_a + ar * 32 + ah) = av0;
        *(float4*)(lds_a + ar * 32 + ah + 8) = av1;
        *(bf16x8*)(lds_b + br * 32 + bs) = wb;
        __syncthreads();
        bf16x8 af0 = *(const bf16x8*)(lds_a + (w * 32 + ml) * 32 + kseg * 8);
        bf16x8 af1 = *(const bf16x8*)(lds_a + (w * 32 + 16 + ml) * 32 + kseg * 8);
#pragma unroll
        for (int ct = 0; ct < 4; ct++) {
            bf16x8 bf_ = *(const bf16x8*)(lds_b + (ct * 16 + ml) * 32 + kseg * 8);
            acc[0][ct] = __builtin_amdgcn_mfma_f32_16x16x32_bf16(af0, bf_, acc[0][ct], 0, 0, 0);
            acc[1][ct] = __builtin_amdgcn_mfma_f32_16x16x32_bf16(af1, bf_, acc[1][ct], 0, 0, 0);
        }
    }

    float bval[4];
#pragma unroll
    for (int ct = 0; ct < 4; ct++)
        bval[ct] = bias ? bias[colBase + ct * 16 + ml] : 0.0f;

#pragma unroll
    for (int rt = 0; rt < 2; rt++) {
#pragma unroll
        for (int reg = 0; reg < 4; reg++) {
            int r = rowBase + w * 32 + rt * 16 + kseg * 4 + reg;
            if (r >= M) continue;
            size_t ro = (size_t)r * N;
#pragma unroll
            for (int ct = 0; ct < 4; ct++) {
                int c = colBase + ct * 16 + ml;
                float v = acc[rt][ct][reg] + bval[ct];
                if constexpr (MODE == 1) v += res[ro + c];
                if constexpr (MODE == 2) v = 0.5f * v * (1.0f + erff(v * 0.70710678118f));
                C[ro + c] = (OutT)v;
            }
        }
    }
}

// ------------------------------------------------------------------ VALU GEMM (head only)
template <int MODE, typename OutT>
__global__ __launch_bounds__(256) void gemm_kernel(const bf16* __restrict__ A,
                                                   const float* __restrict__ W,
                                                   const float* __restrict__ bias,
                                                   const float* res, OutT* C,
                                                   int M, int N, int K) {
    __shared__ float As[32][65];
    __shared__ float Ws[32][65];
    int tid = threadIdx.x;
    int rowBase = blockIdx.y * 64;
    int colBase = blockIdx.x * 64;
    int lr = tid >> 2;
    int lk = (tid & 3) * 8;
    int tx = tid & 15, ty = tid >> 4;
    float acc[4][4] = {};
    for (int k0 = 0; k0 < K; k0 += 32) {
        int gr = rowBase + lr;
        const bf16* asrc = A + (size_t)gr * K + k0 + lk;
        bool aok = (gr < M);
#pragma unroll
        for (int e = 0; e < 8; e++) As[lk + e][lr] = aok ? b2f(asrc[e]) : 0.0f;
        int gc = colBase + lr;
        const float* wsrc = W + (size_t)gc * K + k0 + lk;
        bool wok = (gc < N);
#pragma unroll
        for (int e = 0; e < 8; e++) Ws[lk + e][lr] = wok ? wsrc[e] : 0.0f;
        __syncthreads();
#pragma unroll
        for (int kk = 0; kk < 32; kk++) {
            float a[4], b[4];
#pragma unroll
            for (int i = 0; i < 4; i++) a[i] = As[kk][ty * 4 + i];
#pragma unroll
            for (int j = 0; j < 4; j++) b[j] = Ws[kk][tx * 4 + j];
#pragma unroll
            for (int i = 0; i < 4; i++)
#pragma unroll
                for (int j = 0; j < 4; j++) acc[i][j] += a[i] * b[j];
        }
        __syncthreads();
    }
#pragma unroll
    for (int i = 0; i < 4; i++) {
        int r = rowBase + ty * 4 + i;
        if (r >= M) continue;
#pragma unroll
        for (int j = 0; j < 4; j++) {
            int c = colBase + tx * 4 + j;
            if (c >= N) continue;
            float v = acc[i][j];
            if (bias) v += bias[c];
            if constexpr (MODE == 1) v += res[(size_t)r * N + c];
            if constexpr (MODE == 2) v = 0.5f * v * (1.0f + erff(v * 0.70710678118f));
            C[(size_t)r * N + c] = (OutT)v;
        }
    }
}

// ------------------------------------------------------------------ MFMA attention
#define AKR 208
#define VTS 232
#define PSS 232
__global__ __launch_bounds__(256) void attn_mfma_kernel(const bf16* __restrict__ qkv,
                                                        const float* __restrict__ scale,
                                                        bf16* __restrict__ o) {
    __shared__ __align__(16) short Ks[AKR * 32];
    __shared__ __align__(16) short Vt[32 * VTS];
    __shared__ __align__(16) short Ps[4][16 * PSS];
    int b = blockIdx.x, h = blockIdx.y;
    int tid = threadIdx.x;
    int w = tid >> 6, lane = tid & 63;
    int ml = lane & 15, quad = lane >> 4;

    for (int i = tid; i < 32 * VTS / 2; i += 256) ((int*)Vt)[i] = 0;
    for (int e = lane; e < 16 * 16; e += 64) {
        int r = e >> 4, c = e & 15;
        Ps[w][r * PSS + 208 + c] = 0;
    }
    __syncthreads();
    for (int e = tid; e < AKR * 4; e += 256) {
        int row = e >> 2, seg = e & 3;
        float4 v = {0.0f, 0.0f, 0.0f, 0.0f};
        if (row < N_)
            v = *(const float4*)(qkv + (size_t)(b * N_ + row) * (3 * INNER_) + INNER_ + h * DH_ + seg * 8);
        *(float4*)(Ks + row * 32 + seg * 8) = v;
    }
    for (int e = tid; e < N_ * 32; e += 256) {
        int j = e >> 5, d = e & 31;
        Vt[d * VTS + j] = *(const short*)(qkv + (size_t)(b * N_ + j) * (3 * INNER_) + 2 * INNER_ + h * DH_ + d);
    }
    __syncthreads();

    float sc = scale[h];
    for (int qt = w; qt < 13; qt += 4) {
        int q0 = qt * 16;
        int qrow = q0 + ml;
        if (qrow > N_ - 1) qrow = N_ - 1;
        bf16x8 aq = *(const bf16x8*)(qkv + (size_t)(b * N_ + qrow) * (3 * INNER_) + h * DH_ + quad * 8);
        f32x4 accs[13];
#pragma unroll
        for (int kt = 0; kt < 13; kt++) {
            bf16x8 bk = *(const bf16x8*)(Ks + (kt * 16 + ml) * 32 + quad * 8);
            f32x4 z = {0.0f, 0.0f, 0.0f, 0.0f};
            accs[kt] = __builtin_amdgcn_mfma_f32_16x16x32_bf16(aq, bk, z, 0, 0, 0);
        }
        float rmax[4] = {-1e30f, -1e30f, -1e30f, -1e30f};
#pragma unroll
        for (int kt = 0; kt < 13; kt++) {
            int key = kt * 16 + ml;
#pragma unroll
            for (int reg = 0; reg < 4; reg++) {
                int qg = q0 + quad * 4 + reg;
                bool valid = (key < N_) && (key != qg);
                float s = valid ? accs[kt][reg] * sc : -1e30f;
                accs[kt][reg] = s;
                rmax[reg] = fmaxf(rmax[reg], s);
            }
        }
#pragma unroll
        for (int m = 1; m <= 8; m <<= 1)
#pragma unroll
            for (int reg = 0; reg < 4; reg++)
                rmax[reg] = fmaxf(rmax[reg], __shfl_xor(rmax[reg], m));
        float rsum[4] = {0.0f, 0.0f, 0.0f, 0.0f};
#pragma unroll
        for (int kt = 0; kt < 13; kt++) {
#pragma unroll
            for (int reg = 0; reg < 4; reg++) {
                float wgt = __expf(accs[kt][reg] - rmax[reg]);
                accs[kt][reg] = wgt;
                rsum[reg] += wgt;
            }
        }
#pragma unroll
        for (int m = 1; m <= 8; m <<= 1)
#pragma unroll
            for (int reg = 0; reg < 4; reg++)
                rsum[reg] += __shfl_xor(rsum[reg], m);
#pragma unroll
        for (int kt = 0; kt < 13; kt++)
#pragma unroll
            for (int reg = 0; reg < 4; reg++)
                Ps[w][(quad * 4 + reg) * PSS + kt * 16 + ml] = f2b_raw(accs[kt][reg]);
        f32x4 acco[2] = {{0.0f, 0.0f, 0.0f, 0.0f}, {0.0f, 0.0f, 0.0f, 0.0f}};
#pragma unroll
        for (int kc = 0; kc < 7; kc++) {
            bf16x8 ap = *(const bf16x8*)(Ps[w] + ml * PSS + kc * 32 + quad * 8);
#pragma unroll
            for (int nt = 0; nt < 2; nt++) {
                bf16x8 bv = *(const bf16x8*)(Vt + (nt * 16 + ml) * VTS + kc * 32 + quad * 8);
                acco[nt] = __builtin_amdgcn_mfma_f32_16x16x32_bf16(ap, bv, acco[nt], 0, 0, 0);
            }
        }
#pragma unroll
        for (int reg = 0; reg < 4; reg++) {
            int qg = q0 + quad * 4 + reg;
            if (qg >= N_) continue;
            float inv = 1.0f / rsum[reg];
#pragma unroll
            for (int nt = 0; nt < 2; nt++)
                o[(size_t)(b * N_ + qg) * INNER_ + h * DH_ + nt * 16 + ml] = f2b(acco[nt][reg] * inv);
        }
    }
}

// ------------------------------------------------------------------ diagnostics (f32 out)
__global__ __launch_bounds__(256) void diag_kernel(const float* __restrict__ bufx,
                                                   float* __restrict__ outf,
                                                   int base_marker, int ran) {
    __shared__ int bad;
    if (threadIdx.x == 0) bad = 0;
    __syncthreads();
    if (ran) {
        for (int i = threadIdx.x; i < 4096; i += 256) {
            float v = bufx[i];
            if (!(fabsf(v) < 1e30f)) bad = 1;
        }
    }
    __syncthreads();
    int marker = base_marker + (bad ? 512 : 0);
    if (marker == 0) return;
    int idx = blockIdx.x * 256 + threadIdx.x;
    if (idx > 0 && idx < 64000) outf[idx] = 0.0f;
    if (idx == 0) outf[0] = (float)marker;
}

// ------------------------------------------------------------------ launch
extern "C" void kernel_launch(void* const* d_in, const int* in_sizes, int n_in,
                              void* d_out, int out_size, void* d_ws, size_t ws_size,
                              hipStream_t stream) {
    const float* img     = (const float*)d_in[0];
    const float* patch_w = (const float*)d_in[1];
    const float* patch_b = (const float*)d_in[2];
    const float* pos_emb = (const float*)d_in[3];
    const float* cls_tok = (const float*)d_in[4];
    const float* ln1_g   = (const float*)d_in[5];
    const float* ln1_b   = (const float*)d_in[6];
    const float* qkv_w   = (const float*)d_in[7];
    const float* scale   = (const float*)d_in[8];
    const float* out_w   = (const float*)d_in[9];
    const float* out_b   = (const float*)d_in[10];
    const float* ln2_g   = (const float*)d_in[11];
    const float* ln2_b   = (const float*)d_in[12];
    const float* ff_w1   = (const float*)d_in[13];
    const float* ff_b1   = (const float*)d_in[14];
    const float* ff_w2   = (const float*)d_in[15];
    const float* ff_b2   = (const float*)d_in[16];
    const float* lnf_g   = (const float*)d_in[17];
    const float* lnf_b   = (const float*)d_in[18];
    const float* head_w  = (const float*)d_in[19];
    const float* head_b  = (const float*)d_in[20];

    // Base workspace (proven): 58,146,816 B; fast-path extra bf16 weights -> 101,990,400 B
    // (fast path PROVEN active in round 8: ws_size >= NEED_FAST)
    const size_t NEED = 58146816;
    const size_t NEED_FAST = 101990400;
    char* ws = (char*)d_ws;
    float* buf_x   = (float*)ws;
    bf16*  buf_hb  = (bf16*)(ws + 19365888);
    bf16*  buf_cd  = (bf16*)(ws + 29048832);
    bf16*  meanimg = (bf16*)(ws + 29048832 + 22478848);
    bf16*  buf_cls = (bf16*)(ws + 58097664);
    bf16*  wb_patch = (bf16*)(ws + 58146816);
    bf16*  wb_qkv   = (bf16*)(ws + 59523072);
    bf16*  wb_out   = (bf16*)(ws + 70139904);
    bf16*  wb_ff1   = (bf16*)(ws + 73678848);
    bf16*  wb_ff2   = (bf16*)(ws + 87834624);

    if (ws_size < NEED) {
        diag_kernel<<<250, 256, 0, stream>>>((const float*)d_out, (float*)d_out,
                                             1024 + (int)(ws_size >> 20), 0);
        return;
    }
    const bool fast = (ws_size >= NEED_FAST);

    const int ROWS = B_ * N_;  // 12608
    const int GY = (ROWS + 127) / 128;  // 99

    if (fast) {
        // one-time (per launch) weight conversion f32 -> bf16
        wconv_kernel<<<(688128 / 4 + 255) / 256, 256, 0, stream>>>(patch_w, wb_patch, 688128 / 4);
        wconv_kernel<<<(5308416 / 4 + 255) / 256, 256, 0, stream>>>(qkv_w, wb_qkv, 5308416 / 4);
        wconv_kernel<<<(1769472 / 4 + 255) / 256, 256, 0, stream>>>(out_w, wb_out, 1769472 / 4);
        wconv_kernel<<<(7077888 / 4 + 255) / 256, 256, 0, stream>>>(ff_w1, wb_ff1, 7077888 / 4);
        wconv_kernel<<<(7077888 / 4 + 255) / 256, 256, 0, stream>>>(ff_w2, wb_ff2, 7077888 / 4);

        mean_kernel<<<(B_ * 50176 + 255) / 256, 256, 0, stream>>>(img, meanimg);
        for (int c = 0; c < 2; c++) {
            int bp0 = c * 6272;
            patches_kernel<<<6272, 256, 0, stream>>>(img, meanimg, buf_cd, bp0);
            mgemm3_kernel<0, bf16><<<dim3(3, 49), 256, 0, stream>>>(
                buf_cd, wb_patch, patch_b, nullptr, buf_hb + (size_t)bp0 * DIM_, 6272, DIM_, PD_);
        }
        addpos_kernel<<<(B_ * N_ * DIM_ + 255) / 256, 256, 0, stream>>>(buf_hb, cls_tok, pos_emb, buf_x);

        for (int i = 0; i < DEPTH_; i++) {
            ln_kernel<<<ROWS / 4, 256, 0, stream>>>(buf_x, DIM_, ln1_g + i * DIM_,
                                                    ln1_b + i * DIM_, buf_hb, ROWS);
            mgemm3_kernel<0, bf16><<<dim3(9, GY), 256, 0, stream>>>(
                buf_hb, wb_qkv + (size_t)i * 3 * INNER_ * DIM_, nullptr, nullptr, buf_cd,
                ROWS, 3 * INNER_, DIM_);
            attn_mfma_kernel<<<dim3(B_, H_), 256, 0, stream>>>(buf_cd, scale + i * H_, buf_hb);
            mgemm3_kernel<1, float><<<dim3(3, GY), 256, 0, stream>>>(
                buf_hb, wb_out + (size_t)i * DIM_ * INNER_, out_b + i * DIM_, buf_x, buf_x,
                ROWS, DIM_, INNER_);
            ln_kernel<<<ROWS / 4, 256, 0, stream>>>(buf_x, DIM_, ln2_g + i * DIM_,
                                                    ln2_b + i * DIM_, buf_hb, ROWS);
            int base = 0;
            for (int c = 0; c < 2; c++) {
                int mrows = (c == 0) ? 6336 : 6272;
                int gy = (mrows + 127) / 128;
                mgemm3_kernel<2, bf16><<<dim3(12, gy), 256, 0, stream>>>(
                    buf_hb + (size_t)base * DIM_, wb_ff1 + (size_t)i * MLP_ * DIM_,
                    ff_b1 + i * MLP_, nullptr, buf_cd, mrows, MLP_, DIM_);
                mgemm3_kernel<1, float><<<dim3(3, gy), 256, 0, stream>>>(
                    buf_cd, wb_ff2 + (size_t)i * DIM_ * MLP_, ff_b2 + i * DIM_,
                    buf_x + (size_t)base * DIM_, buf_x + (size_t)base * DIM_, mrows, DIM_, MLP_);
                base += mrows;
            }
        }
    } else {
        // fallback: round-7 proven path (W f32 in-kernel convert)
        mean_kernel<<<(B_ * 50176 + 255) / 256, 256, 0, stream>>>(img, meanimg);
        for (int c = 0; c < 2; c++) {
            int bp0 = c * 6272;
            patches_kernel<<<6272, 256, 0, stream>>>(img, meanimg, buf_cd, bp0);
            mgemm_kernel<0, bf16><<<dim3(DIM_ / 64, 49), 256, 0, stream>>>(
                buf_cd, patch_w, patch_b, nullptr, buf_hb + (size_t)bp0 * DIM_, 6272, DIM_, PD_);
        }
        addpos_kernel<<<(B_ * N_ * DIM_ + 255) / 256, 256, 0, stream>>>(buf_hb, cls_tok, pos_emb, buf_x);

        for (int i = 0; i < DEPTH_; i++) {
            ln_kernel<<<ROWS / 4, 256, 0, stream>>>(buf_x, DIM_, ln1_g + i * DIM_,
                                                    ln1_b + i * DIM_, buf_hb, ROWS);
            mgemm_kernel<0, bf16><<<dim3((3 * INNER_) / 64, GY), 256, 0, stream>>>(
                buf_hb, qkv_w + (size_t)i * 3 * INNER_ * DIM_, nullptr, nullptr, buf_cd,
                ROWS, 3 * INNER_, DIM_);
            attn_mfma_kernel<<<dim3(B_, H_), 256, 0, stream>>>(buf_cd, scale + i * H_, buf_hb);
            mgemm_kernel<1, float><<<dim3(DIM_ / 64, GY), 256, 0, stream>>>(
                buf_hb, out_w + (size_t)i * DIM_ * INNER_, out_b + i * DIM_, buf_x, buf_x,
                ROWS, DIM_, INNER_);
            ln_kernel<<<ROWS / 4, 256, 0, stream>>>(buf_x, DIM_, ln2_g + i * DIM_,
                                                    ln2_b + i * DIM_, buf_hb, ROWS);
            int base = 0;
            for (int c = 0; c < 2; c++) {
                int mrows = (c == 0) ? 6336 : 6272;
                int gy = (mrows + 127) / 128;
                mgemm_kernel<2, bf16><<<dim3(MLP_ / 64, gy), 256, 0, stream>>>(
                    buf_hb + (size_t)base * DIM_, ff_w1 + (size_t)i * MLP_ * DIM_,
                    ff_b1 + i * MLP_, nullptr, buf_cd, mrows, MLP_, DIM_);
                mgemm_kernel<1, float><<<dim3(DIM_ / 64, gy), 256, 0, stream>>>(
                    buf_cd, ff_w2 + (size_t)i * DIM_ * MLP_, ff_b2 + i * DIM_,
                    buf_x + (size_t)base * DIM_, buf_x + (size_t)base * DIM_, mrows, DIM_, MLP_);
                base += mrows;
            }
        }
    }

    ln_kernel<<<B_ / 4, 256, 0, stream>>>(buf_x, (long)N_ * DIM_, lnf_g, lnf_b, buf_cls, B_);
    gemm_kernel<0, float><<<dim3((NCLS_ + 63) / 64, 1), 256, 0, stream>>>(
        buf_cls, head_w, head_b, nullptr, (float*)d_out, B_, NCLS_, DIM_);

    diag_kernel<<<250, 256, 0, stream>>>(buf_x, (float*)d_out, 0, 1);
}

// Round 10
// 2401.786 us; speedup vs baseline: 6.7413x; 1.2285x over previous
//
#include <hip/hip_runtime.h>
#include <hip/hip_bf16.h>

// Model constants
#define B_ 64
#define IMG_ 224
#define P_ 16
#define G_ 14
#define NP_ 196
#define N_ 197
#define DIM_ 384
#define DEPTH_ 12
#define H_ 12
#define DH_ 32
#define INNER_ 384
#define MLP_ 1536
#define NCLS_ 1000
#define PD_ 1792
#define EPS_ 1e-5f

typedef __hip_bfloat16 bf16;
using bf16x8 = __attribute__((ext_vector_type(8))) short;   // 8 bf16 (4 VGPRs)
using f32x4  = __attribute__((ext_vector_type(4))) float;   // MFMA acc

typedef __attribute__((address_space(1))) const void gas_void;
typedef __attribute__((address_space(3))) void las_void;

__device__ __forceinline__ float b2f(bf16 x) { return __bfloat162float(x); }
__device__ __forceinline__ bf16 f2b(float x) { return __float2bfloat16(x); }
__device__ __forceinline__ short f2b_raw(float f) {
    unsigned x = __float_as_uint(f);
    unsigned r = (x + 0x7FFFu + ((x >> 16) & 1u)) >> 16;
    return (short)r;
}
// raw workgroup barrier WITHOUT implicit vmcnt(0) drain
__device__ __forceinline__ void barrier_raw() {
    asm volatile("s_barrier" ::: "memory");
}
__device__ __forceinline__ void waitcnt_vm4() {
    asm volatile("s_waitcnt vmcnt(4)" ::: "memory");
}
__device__ __forceinline__ void waitcnt_vm0() {
    asm volatile("s_waitcnt vmcnt(0)" ::: "memory");
}

// ---------------------------------------------------------------- weight f32->bf16
__global__ __launch_bounds__(256) void wconv_kernel(const float* __restrict__ src,
                                                    bf16* __restrict__ dst, int n4) {
    int i = blockIdx.x * 256 + threadIdx.x;
    if (i >= n4) return;
    float4 v = ((const float4*)src)[i];
    short4 o;
    o.x = f2b_raw(v.x); o.y = f2b_raw(v.y);
    o.z = f2b_raw(v.z); o.w = f2b_raw(v.w);
    ((short4*)dst)[i] = o;
}

// ---------------------------------------------------------------- mean image (bf16)
__global__ __launch_bounds__(256) void mean_kernel(const float* __restrict__ img,
                                                   bf16* __restrict__ meanimg) {
    int idx = blockIdx.x * 256 + threadIdx.x;
    if (idx >= B_ * 50176) return;
    int b = idx / 50176;
    int yx = idx - b * 50176;
    const float* p = img + (size_t)b * 3 * 50176 + yx;
    meanimg[idx] = f2b((p[0] + p[50176] + p[100352]) * (1.0f / 3.0f));
}

// ------------------------------------------------------------- patch matrix (chunked)
__global__ __launch_bounds__(256) void patches_kernel(const float* __restrict__ img,
                                                      const bf16* __restrict__ meanimg,
                                                      bf16* __restrict__ patches,
                                                      int bp0, int nbp) {
    int idx = blockIdx.x * 256 + threadIdx.x;
    if (idx >= nbp * 256) return;
    int pix = idx & 255;
    int px = pix & 15, py = pix >> 4;
    int lbp = idx >> 8;
    int bp = bp0 + lbp;
    int p = bp % NP_;
    int b = bp / NP_;
    int gy = p / G_, gx = p - gy * G_;
    int y = gy * P_ + py, x = gx * P_ + px;
    const float* ib = img + (size_t)b * 3 * 50176 + y * 224 + x;
    bf16* out = patches + (size_t)lbp * PD_ + pix * 7;
    out[0] = f2b(ib[0]);
    out[1] = f2b(ib[50176]);
    out[2] = f2b(ib[100352]);
    const bf16* mb = meanimg + (size_t)b * 50176;
    out[3] = (x >= 8)  ? mb[y * 224 + x - 8]   : f2b(0.0f);   // l2
    out[4] = (x < 216) ? mb[y * 224 + x + 8]   : f2b(0.0f);   // r2
    out[5] = (y >= 8)  ? mb[(y - 8) * 224 + x] : f2b(0.0f);   // t2
    out[6] = (y < 216) ? mb[(y + 8) * 224 + x] : f2b(0.0f);   // b2
}

// --------------------------------------------------- cls + pos_emb assembly
__global__ __launch_bounds__(256) void addpos_kernel(const bf16* __restrict__ pe,
                                                     const float* __restrict__ cls_tok,
                                                     const float* __restrict__ pos_emb,
                                                     float* __restrict__ x) {
    int idx = blockIdx.x * 256 + threadIdx.x;
    if (idx >= B_ * N_ * DIM_) return;
    int c = idx % DIM_;
    int r = idx / DIM_;
    int t = r % N_;
    int b = r / N_;
    float v = (t == 0) ? cls_tok[c]
                       : b2f(pe[((size_t)(b * NP_ + t - 1)) * DIM_ + c]);
    x[idx] = v + pos_emb[t * DIM_ + c];
}

// ------------------------------------------------------------------ layernorm
__global__ __launch_bounds__(256) void ln_kernel(const float* __restrict__ in,
                                                 long in_stride,
                                                 const float* __restrict__ g,
                                                 const float* __restrict__ bb,
                                                 bf16* __restrict__ out, int rows) {
    int wave = threadIdx.x >> 6;
    int lane = threadIdx.x & 63;
    int row = blockIdx.x * 4 + wave;
    if (row >= rows) return;
    const float* p = in + (size_t)row * in_stride;
    float v[6];
    float s = 0.0f, s2 = 0.0f;
#pragma unroll
    for (int i = 0; i < 6; i++) {
        v[i] = p[lane + 64 * i];
        s += v[i];
        s2 += v[i] * v[i];
    }
#pragma unroll
    for (int m = 32; m >= 1; m >>= 1) {
        s += __shfl_xor(s, m);
        s2 += __shfl_xor(s2, m);
    }
    float mu = s * (1.0f / 384.0f);
    float var = s2 * (1.0f / 384.0f) - mu * mu;
    var = fmaxf(var, 0.0f);
    float inv = rsqrtf(var + EPS_);
    bf16* q = out + (size_t)row * DIM_;
#pragma unroll
    for (int i = 0; i < 6; i++) {
        int c = lane + 64 * i;
        q[c] = f2b((v[i] - mu) * inv * g[c] + bb[c]);
    }
}

// ------------------------------------------------------------------ head GEMM (wave/col)
// out[64,1000] = cls[64,384](bf16) @ W[1000,384]^T + b. One wave per output column:
// lane-parallel K, butterfly reduce per row, lane r keeps row r, coalesced loads.
__global__ __launch_bounds__(256) void head_kernel(const bf16* __restrict__ cls,
                                                   const float* __restrict__ W,
                                                   const float* __restrict__ bias,
                                                   float* __restrict__ out) {
    int wv = threadIdx.x >> 6, lane = threadIdx.x & 63;
    int col = blockIdx.x * 4 + wv;
    if (col >= NCLS_) return;
    const float* wp = W + (size_t)col * DIM_;
    float wreg[6];
#pragma unroll
    for (int i = 0; i < 6; i++) wreg[i] = wp[i * 64 + lane];
    float hb = bias[col];
    float res = 0.0f;
    for (int r = 0; r < 64; r++) {
        const bf16* ar = cls + r * DIM_;
        float s = 0.0f;
#pragma unroll
        for (int i = 0; i < 6; i++) s += b2f(ar[i * 64 + lane]) * wreg[i];
#pragma unroll
        for (int m = 32; m >= 1; m >>= 1) s += __shfl_xor(s, m);
        if (lane == r) res = s + hb;
    }
    out[(size_t)lane * NCLS_ + col] = res;
}

// ------------------------------------------------------------------ MFMA GEMM v3 (pipelined)
// C[M,N] = A[M,K] @ W[N,K]^T, both bf16. BM=128 BN=128 BK=32; double-buffered LDS,
// prefetch via global_load_lds; raw s_barrier + vmcnt(4) keeps prefetch in flight.
// MODE 0: bias. 1: bias+res(f32). 2: bias+exact GELU. N%128==0, K%32==0, K>=64.
template <int MODE, typename OutT>
__global__ __launch_bounds__(256) void mgemm3_kernel(const bf16* __restrict__ A,
                                                     const bf16* __restrict__ W,
                                                     const float* __restrict__ bias,
                                                     const float* __restrict__ res,
                                                     OutT* __restrict__ C,
                                                     int M, int N, int K) {
    __shared__ __align__(16) short lds_a[2][128 * 32];   // 2 x 8 KB
    __shared__ __align__(16) short lds_b[2][128 * 32];   // 2 x 8 KB
    int tid = threadIdx.x;
    int wv = tid >> 6, lane = tid & 63;
    int ml = lane & 15, quad = lane >> 4;
    int rowBase = blockIdx.y * 128, colBase = blockIdx.x * 128;

    int srow = wv * 16 + (lane >> 2);
    int kcol = (lane & 3) * 8;
    int ar0 = rowBase + srow;       if (ar0 >= M) ar0 = M - 1;
    int ar1 = rowBase + 64 + srow;  if (ar1 >= M) ar1 = M - 1;
    const bf16* a0 = A + (size_t)ar0 * K + kcol;
    const bf16* a1 = A + (size_t)ar1 * K + kcol;
    const bf16* b0 = W + (size_t)(colBase + srow) * K + kcol;
    const bf16* b1 = W + (size_t)(colBase + 64 + srow) * K + kcol;
    short* laA[2]  = { lds_a[0] + (wv * 16) * 32,      lds_a[1] + (wv * 16) * 32 };
    short* laA2[2] = { lds_a[0] + (64 + wv * 16) * 32, lds_a[1] + (64 + wv * 16) * 32 };
    short* lbB[2]  = { lds_b[0] + (wv * 16) * 32,      lds_b[1] + (wv * 16) * 32 };
    short* lbB2[2] = { lds_b[0] + (64 + wv * 16) * 32, lds_b[1] + (64 + wv * 16) * 32 };

#define ISSUE_TILE(buf, k0)                                                                   \
    do {                                                                                      \
        __builtin_amdgcn_global_load_lds((gas_void*)(a0 + (k0)), (las_void*)laA[buf], 16, 0, 0);  \
        __builtin_amdgcn_global_load_lds((gas_void*)(a1 + (k0)), (las_void*)laA2[buf], 16, 0, 0); \
        __builtin_amdgcn_global_load_lds((gas_void*)(b0 + (k0)), (las_void*)lbB[buf], 16, 0, 0);  \
        __builtin_amdgcn_global_load_lds((gas_void*)(b1 + (k0)), (las_void*)lbB2[buf], 16, 0, 0); \
    } while (0)

    int wr = (wv >> 1) * 64, wc = (wv & 1) * 64;
    f32x4 acc[4][4] = {};
    int NK = K >> 5;

    ISSUE_TILE(0, 0);
    ISSUE_TILE(1, 32);

    for (int k = 0; k < NK; k++) {
        if (k + 1 < NK) waitcnt_vm4();
        else            waitcnt_vm0();
        barrier_raw();
        int cb = k & 1;
        bf16x8 af[4], bfr[4];
#pragma unroll
        for (int rg = 0; rg < 4; rg++)
            af[rg] = *(const bf16x8*)(lds_a[cb] + (wr + rg * 16 + ml) * 32 + quad * 8);
#pragma unroll
        for (int cg = 0; cg < 4; cg++)
            bfr[cg] = *(const bf16x8*)(lds_b[cb] + (wc + cg * 16 + ml) * 32 + quad * 8);
#pragma unroll
        for (int rg = 0; rg < 4; rg++)
#pragma unroll
            for (int cg = 0; cg < 4; cg++)
                acc[rg][cg] = __builtin_amdgcn_mfma_f32_16x16x32_bf16(af[rg], bfr[cg], acc[rg][cg], 0, 0, 0);
        barrier_raw();
        if (k + 2 < NK) ISSUE_TILE(cb, (k + 2) * 32);
    }
#undef ISSUE_TILE

    float bval[4];
#pragma unroll
    for (int cg = 0; cg < 4; cg++)
        bval[cg] = bias ? bias[colBase + wc + cg * 16 + ml] : 0.0f;

#pragma unroll
    for (int rg = 0; rg < 4; rg++) {
#pragma unroll
        for (int reg = 0; reg < 4; reg++) {
            int r = rowBase + wr + rg * 16 + quad * 4 + reg;
            if (r >= M) continue;
            size_t ro = (size_t)r * N;
#pragma unroll
            for (int cg = 0; cg < 4; cg++) {
                int c = colBase + wc + cg * 16 + ml;
                float v = acc[rg][cg][reg] + bval[cg];
                if constexpr (MODE == 1) v += res[ro + c];
                if constexpr (MODE == 2) v = 0.5f * v * (1.0f + erff(v * 0.70710678118f));
                C[ro + c] = (OutT)v;
            }
        }
    }
}

// ------------------------------------------------------------------ MFMA GEMM v1 (base tier, W f32)
template <int MODE, typename OutT>
__global__ __launch_bounds__(256) void mgemm_kernel(const bf16* __restrict__ A,
                                                    const float* __restrict__ W,
                                                    const float* __restrict__ bias,
                                                    const float* __restrict__ res,
                                                    OutT* __restrict__ C,
                                                    int M, int N, int K) {
    __shared__ __align__(16) short lds_a[128 * 32];
    __shared__ __align__(16) short lds_b[64 * 32];
    int tid = threadIdx.x;
    int rowBase = blockIdx.y * 128;
    int colBase = blockIdx.x * 64;
    int w = tid >> 6, lane = tid & 63;
    int ml = lane & 15, kseg = lane >> 4;

    int ar = tid >> 1;
    int ah = (tid & 1) * 16;
    int agr = rowBase + ar;
    if (agr > M - 1) agr = M - 1;
    const float4* asrc_base = (const float4*)(A + (size_t)agr * K + ah);
    int br = tid >> 2;
    int bs = (tid & 3) * 8;
    const float4* wsrc_base = (const float4*)(W + (size_t)(colBase + br) * K + bs);

    f32x4 acc[2][4] = {};

    for (int k0 = 0; k0 < K; k0 += 32) {
        const float4* asrc = (const float4*)((const bf16*)asrc_base + k0);
        float4 av0 = asrc[0];
        float4 av1 = asrc[1];
        const float4* wsrc = (const float4*)((const float*)wsrc_base + k0);
        float4 w0 = wsrc[0];
        float4 w1 = wsrc[1];
        bf16x8 wb;
        wb[0] = f2b_raw(w0.x); wb[1] = f2b_raw(w0.y);
        wb[2] = f2b_raw(w0.z); wb[3] = f2b_raw(w0.w);
        wb[4] = f2b_raw(w1.x); wb[5] = f2b_raw(w1.y);
        wb[6] = f2b_raw(w1.z); wb[7] = f2b_raw(w1.w);
        __syncthreads();
        *(float4*)(lds_a + ar * 32 + ah) = av0;
        *(float4*)(lds_a + ar * 32 + ah + 8) = av1;
        *(bf16x8*)(lds_b + br * 32 + bs) = wb;
        __syncthreads();
        bf16x8 af0 = *(const bf16x8*)(lds_a + (w * 32 + ml) * 32 + kseg * 8);
        bf16x8 af1 = *(const bf16x8*)(lds_a + (w * 32 + 16 + ml) * 32 + kseg * 8);
#pragma unroll
        for (int ct = 0; ct < 4; ct++) {
            bf16x8 bf_ = *(const bf16x8*)(lds_b + (ct * 16 + ml) * 32 + kseg * 8);
            acc[0][ct] = __builtin_amdgcn_mfma_f32_16x16x32_bf16(af0, bf_, acc[0][ct], 0, 0, 0);
            acc[1][ct] = __builtin_amdgcn_mfma_f32_16x16x32_bf16(af1, bf_, acc[1][ct], 0, 0, 0);
        }
    }

    float bval[4];
#pragma unroll
    for (int ct = 0; ct < 4; ct++)
        bval[ct] = bias ? bias[colBase + ct * 16 + ml] : 0.0f;

#pragma unroll
    for (int rt = 0; rt < 2; rt++) {
#pragma unroll
        for (int reg = 0; reg < 4; reg++) {
            int r = rowBase + w * 32 + rt * 16 + kseg * 4 + reg;
            if (r >= M) continue;
            size_t ro = (size_t)r * N;
#pragma unroll
            for (int ct = 0; ct < 4; ct++) {
                int c = colBase + ct * 16 + ml;
                float v = acc[rt][ct][reg] + bval[ct];
                if constexpr (MODE == 1) v += res[ro + c];
                if constexpr (MODE == 2) v = 0.5f * v * (1.0f + erff(v * 0.70710678118f));
                C[ro + c] = (OutT)v;
            }
        }
    }
}

// ------------------------------------------------------------------ MFMA attention
#define AKR 208
#define VTS 232
#define PSS 232
__global__ __launch_bounds__(256) void attn_mfma_kernel(const bf16* __restrict__ qkv,
                                                        const float* __restrict__ scale,
                                                        bf16* __restrict__ o) {
    __shared__ __align__(16) short Ks[AKR * 32];
    __shared__ __align__(16) short Vt[32 * VTS];
    __shared__ __align__(16) short Ps[4][16 * PSS];
    int b = blockIdx.x, h = blockIdx.y;
    int tid = threadIdx.x;
    int w = tid >> 6, lane = tid & 63;
    int ml = lane & 15, quad = lane >> 4;

    for (int i = tid; i < 32 * VTS / 2; i += 256) ((int*)Vt)[i] = 0;
    for (int e = lane; e < 16 * 16; e += 64) {
        int r = e >> 4, c = e & 15;
        Ps[w][r * PSS + 208 + c] = 0;
    }
    __syncthreads();
    for (int e = tid; e < AKR * 4; e += 256) {
        int row = e >> 2, seg = e & 3;
        float4 v = {0.0f, 0.0f, 0.0f, 0.0f};
        if (row < N_)
            v = *(const float4*)(qkv + (size_t)(b * N_ + row) * (3 * INNER_) + INNER_ + h * DH_ + seg * 8);
        *(float4*)(Ks + row * 32 + seg * 8) = v;
    }
    for (int e = tid; e < N_ * 32; e += 256) {
        int j = e >> 5, d = e & 31;
        Vt[d * VTS + j] = *(const short*)(qkv + (size_t)(b * N_ + j) * (3 * INNER_) + 2 * INNER_ + h * DH_ + d);
    }
    __syncthreads();

    float sc = scale[h];
    for (int qt = w; qt < 13; qt += 4) {
        int q0 = qt * 16;
        int qrow = q0 + ml;
        if (qrow > N_ - 1) qrow = N_ - 1;
        bf16x8 aq = *(const bf16x8*)(qkv + (size_t)(b * N_ + qrow) * (3 * INNER_) + h * DH_ + quad * 8);
        f32x4 accs[13];
#pragma unroll
        for (int kt = 0; kt < 13; kt++) {
            bf16x8 bk = *(const bf16x8*)(Ks + (kt * 16 + ml) * 32 + quad * 8);
            f32x4 z = {0.0f, 0.0f, 0.0f, 0.0f};
            accs[kt] = __builtin_amdgcn_mfma_f32_16x16x32_bf16(aq, bk, z, 0, 0, 0);
        }
        float rmax[4] = {-1e30f, -1e30f, -1e30f, -1e30f};
#pragma unroll
        for (int kt = 0; kt < 13; kt++) {
            int key = kt * 16 + ml;
#pragma unroll
            for (int reg = 0; reg < 4; reg++) {
                int qg = q0 + quad * 4 + reg;
                bool valid = (key < N_) && (key != qg);
                float s = valid ? accs[kt][reg] * sc : -1e30f;
                accs[kt][reg] = s;
                rmax[reg] = fmaxf(rmax[reg], s);
            }
        }
#pragma unroll
        for (int m = 1; m <= 8; m <<= 1)
#pragma unroll
            for (int reg = 0; reg < 4; reg++)
                rmax[reg] = fmaxf(rmax[reg], __shfl_xor(rmax[reg], m));
        float rsum[4] = {0.0f, 0.0f, 0.0f, 0.0f};
#pragma unroll
        for (int kt = 0; kt < 13; kt++) {
#pragma unroll
            for (int reg = 0; reg < 4; reg++) {
                float wgt = __expf(accs[kt][reg] - rmax[reg]);
                accs[kt][reg] = wgt;
                rsum[reg] += wgt;
            }
        }
#pragma unroll
        for (int m = 1; m <= 8; m <<= 1)
#pragma unroll
            for (int reg = 0; reg < 4; reg++)
                rsum[reg] += __shfl_xor(rsum[reg], m);
#pragma unroll
        for (int kt = 0; kt < 13; kt++)
#pragma unroll
            for (int reg = 0; reg < 4; reg++)
                Ps[w][(quad * 4 + reg) * PSS + kt * 16 + ml] = f2b_raw(accs[kt][reg]);
        f32x4 acco[2] = {{0.0f, 0.0f, 0.0f, 0.0f}, {0.0f, 0.0f, 0.0f, 0.0f}};
#pragma unroll
        for (int kc = 0; kc < 7; kc++) {
            bf16x8 ap = *(const bf16x8*)(Ps[w] + ml * PSS + kc * 32 + quad * 8);
#pragma unroll
            for (int nt = 0; nt < 2; nt++) {
                bf16x8 bv = *(const bf16x8*)(Vt + (nt * 16 + ml) * VTS + kc * 32 + quad * 8);
                acco[nt] = __builtin_amdgcn_mfma_f32_16x16x32_bf16(ap, bv, acco[nt], 0, 0, 0);
            }
        }
#pragma unroll
        for (int reg = 0; reg < 4; reg++) {
            int qg = q0 + quad * 4 + reg;
            if (qg >= N_) continue;
            float inv = 1.0f / rsum[reg];
#pragma unroll
            for (int nt = 0; nt < 2; nt++)
                o[(size_t)(b * N_ + qg) * INNER_ + h * DH_ + nt * 16 + ml] = f2b(acco[nt][reg] * inv);
        }
    }
}

// ------------------------------------------------------------------ diagnostics (f32 out)
__global__ __launch_bounds__(256) void diag_kernel(const float* __restrict__ bufx,
                                                   float* __restrict__ outf,
                                                   int base_marker, int ran) {
    __shared__ int bad;
    if (threadIdx.x == 0) bad = 0;
    __syncthreads();
    if (ran) {
        for (int i = threadIdx.x; i < 4096; i += 256) {
            float v = bufx[i];
            if (!(fabsf(v) < 1e30f)) bad = 1;
        }
    }
    __syncthreads();
    int marker = base_marker + (bad ? 512 : 0);
    if (marker == 0) return;
    int idx = blockIdx.x * 256 + threadIdx.x;
    if (idx > 0 && idx < 64000) outf[idx] = 0.0f;
    if (idx == 0) outf[0] = (float)marker;
}

// ------------------------------------------------------------------ launch
extern "C" void kernel_launch(void* const* d_in, const int* in_sizes, int n_in,
                              void* d_out, int out_size, void* d_ws, size_t ws_size,
                              hipStream_t stream) {
    const float* img     = (const float*)d_in[0];
    const float* patch_w = (const float*)d_in[1];
    const float* patch_b = (const float*)d_in[2];
    const float* pos_emb = (const float*)d_in[3];
    const float* cls_tok = (const float*)d_in[4];
    const float* ln1_g   = (const float*)d_in[5];
    const float* ln1_b   = (const float*)d_in[6];
    const float* qkv_w   = (const float*)d_in[7];
    const float* scale   = (const float*)d_in[8];
    const float* out_w   = (const float*)d_in[9];
    const float* out_b   = (const float*)d_in[10];
    const float* ln2_g   = (const float*)d_in[11];
    const float* ln2_b   = (const float*)d_in[12];
    const float* ff_w1   = (const float*)d_in[13];
    const float* ff_b1   = (const float*)d_in[14];
    const float* ff_w2   = (const float*)d_in[15];
    const float* ff_b2   = (const float*)d_in[16];
    const float* lnf_g   = (const float*)d_in[17];
    const float* lnf_b   = (const float*)d_in[18];
    const float* head_w  = (const float*)d_in[19];
    const float* head_b  = (const float*)d_in[20];

    // Tiers:
    //  base  (>= 58,146,816):  round-7 proven path, v1 kernels
    //  FAST  (>= 101,990,400): round-9 proven path (bf16 weights, chunked FF/patches)
    //  FULL  (>= 140,722,176): dedicated full ffmid + single-dispatch patches/FF
    //  (harness fill evidence: ws = 256 MiB -> FULL expected active)
    const size_t NEED      = 58146816;
    const size_t NEED_FAST = 101990400;
    const size_t NEED_FULL = 140722176;
    char* ws = (char*)d_ws;
    const int ROWS = B_ * N_;  // 12608
    const int GY = (ROWS + 127) / 128;  // 99

    if (ws_size < NEED) {
        diag_kernel<<<250, 256, 0, stream>>>((const float*)d_out, (float*)d_out,
                                             1024 + (int)(ws_size >> 20), 0);
        return;
    }

    float* buf_x  = (float*)ws;                    // 19,365,888 (all tiers)
    bf16*  buf_hb = (bf16*)(ws + 19365888);        //  9,682,944 (all tiers)

    if (ws_size >= NEED_FAST) {
        // ---- bf16-weight tiers (FAST / FULL) ----
        bool full = (ws_size >= NEED_FULL);
        bf16 *buf_qkv, *buf_ff, *buf_patch, *meanimg, *buf_cls;
        bf16 *wb_patch, *wb_qkv, *wb_out, *wb_ff1, *wb_ff2;
        int pchunks, fchunks;
        if (full) {
            buf_qkv  = (bf16*)(ws + 29048832);               // 29,048,832
            buf_ff   = (bf16*)(ws + 58097664);               // 38,731,776
            buf_patch= (bf16*)(ws + 29048832);               // alias qkv+ff (44,957,696)
            meanimg  = (bf16*)(ws + 74006528);               // 6,422,528 (inside alias)
            wb_patch = (bf16*)(ws + 96829440);
            wb_qkv   = (bf16*)(ws + 98205696);
            wb_out   = (bf16*)(ws + 108822528);
            wb_ff1   = (bf16*)(ws + 112361472);
            wb_ff2   = (bf16*)(ws + 126517248);
            buf_cls  = (bf16*)(ws + 140673024);
            pchunks = 1; fchunks = 1;
        } else {
            buf_qkv  = (bf16*)(ws + 29048832);               // 29,048,832 shared region
            buf_ff   = (bf16*)(ws + 29048832);
            buf_patch= (bf16*)(ws + 29048832);
            meanimg  = (bf16*)(ws + 29048832 + 22478848);
            buf_cls  = (bf16*)(ws + 58097664);
            wb_patch = (bf16*)(ws + 58146816);
            wb_qkv   = (bf16*)(ws + 59523072);
            wb_out   = (bf16*)(ws + 70139904);
            wb_ff1   = (bf16*)(ws + 73678848);
            wb_ff2   = (bf16*)(ws + 87834624);
            pchunks = 2; fchunks = 2;
        }

        wconv_kernel<<<(688128 / 4 + 255) / 256, 256, 0, stream>>>(patch_w, wb_patch, 688128 / 4);
        wconv_kernel<<<(5308416 / 4 + 255) / 256, 256, 0, stream>>>(qkv_w, wb_qkv, 5308416 / 4);
        wconv_kernel<<<(1769472 / 4 + 255) / 256, 256, 0, stream>>>(out_w, wb_out, 1769472 / 4);
        wconv_kernel<<<(7077888 / 4 + 255) / 256, 256, 0, stream>>>(ff_w1, wb_ff1, 7077888 / 4);
        wconv_kernel<<<(7077888 / 4 + 255) / 256, 256, 0, stream>>>(ff_w2, wb_ff2, 7077888 / 4);

        mean_kernel<<<(B_ * 50176 + 255) / 256, 256, 0, stream>>>(img, meanimg);
        for (int c = 0; c < pchunks; c++) {
            int bp0 = c * (12544 / pchunks);
            int nbp = 12544 / pchunks;
            patches_kernel<<<nbp, 256, 0, stream>>>(img, meanimg, buf_patch, bp0, nbp);
            mgemm3_kernel<0, bf16><<<dim3(3, (nbp + 127) / 128), 256, 0, stream>>>(
                buf_patch, wb_patch, patch_b, nullptr, buf_hb + (size_t)bp0 * DIM_, nbp, DIM_, PD_);
        }
        addpos_kernel<<<(B_ * N_ * DIM_ + 255) / 256, 256, 0, stream>>>(buf_hb, cls_tok, pos_emb, buf_x);

        for (int i = 0; i < DEPTH_; i++) {
            ln_kernel<<<ROWS / 4, 256, 0, stream>>>(buf_x, DIM_, ln1_g + i * DIM_,
                                                    ln1_b + i * DIM_, buf_hb, ROWS);
            mgemm3_kernel<0, bf16><<<dim3(9, GY), 256, 0, stream>>>(
                buf_hb, wb_qkv + (size_t)i * 3 * INNER_ * DIM_, nullptr, nullptr, buf_qkv,
                ROWS, 3 * INNER_, DIM_);
            attn_mfma_kernel<<<dim3(B_, H_), 256, 0, stream>>>(buf_qkv, scale + i * H_, buf_hb);
            mgemm3_kernel<1, float><<<dim3(3, GY), 256, 0, stream>>>(
                buf_hb, wb_out + (size_t)i * DIM_ * INNER_, out_b + i * DIM_, buf_x, buf_x,
                ROWS, DIM_, INNER_);
            ln_kernel<<<ROWS / 4, 256, 0, stream>>>(buf_x, DIM_, ln2_g + i * DIM_,
                                                    ln2_b + i * DIM_, buf_hb, ROWS);
            int base = 0;
            for (int c = 0; c < fchunks; c++) {
                int mrows = (fchunks == 1) ? ROWS : ((c == 0) ? 6336 : 6272);
                int gy = (mrows + 127) / 128;
                mgemm3_kernel<2, bf16><<<dim3(12, gy), 256, 0, stream>>>(
                    buf_hb + (size_t)base * DIM_, wb_ff1 + (size_t)i * MLP_ * DIM_,
                    ff_b1 + i * MLP_, nullptr, buf_ff, mrows, MLP_, DIM_);
                mgemm3_kernel<1, float><<<dim3(3, gy), 256, 0, stream>>>(
                    buf_ff, wb_ff2 + (size_t)i * DIM_ * MLP_, ff_b2 + i * DIM_,
                    buf_x + (size_t)base * DIM_, buf_x + (size_t)base * DIM_, mrows, DIM_, MLP_);
                base += mrows;
            }
        }

        ln_kernel<<<B_ / 4, 256, 0, stream>>>(buf_x, (long)N_ * DIM_, lnf_g, lnf_b, buf_cls, B_);
        head_kernel<<<250, 256, 0, stream>>>(buf_cls, head_w, head_b, (float*)d_out);
        diag_kernel<<<250, 256, 0, stream>>>(buf_x, (float*)d_out, 0, 1);
        return;
    }

    // ---- base tier: round-7 proven path (W f32 in-kernel convert) ----
    bf16* buf_cd   = (bf16*)(ws + 29048832);
    bf16* meanimg  = (bf16*)(ws + 29048832 + 22478848);
    bf16* buf_cls  = (bf16*)(ws + 58097664);

    mean_kernel<<<(B_ * 50176 + 255) / 256, 256, 0, stream>>>(img, meanimg);
    for (int c = 0; c < 2; c++) {
        int bp0 = c * 6272;
        patches_kernel<<<6272, 256, 0, stream>>>(img, meanimg, buf_cd, bp0, 6272);
        mgemm_kernel<0, bf16><<<dim3(DIM_ / 64, 49), 256, 0, stream>>>(
            buf_cd, patch_w, patch_b, nullptr, buf_hb + (size_t)bp0 * DIM_, 6272, DIM_, PD_);
    }
    addpos_kernel<<<(B_ * N_ * DIM_ + 255) / 256, 256, 0, stream>>>(buf_hb, cls_tok, pos_emb, buf_x);

    for (int i = 0; i < DEPTH_; i++) {
        ln_kernel<<<ROWS / 4, 256, 0, stream>>>(buf_x, DIM_, ln1_g + i * DIM_,
                                                ln1_b + i * DIM_, buf_hb, ROWS);
        mgemm_kernel<0, bf16><<<dim3((3 * INNER_) / 64, GY), 256, 0, stream>>>(
            buf_hb, qkv_w + (size_t)i * 3 * INNER_ * DIM_, nullptr, nullptr, buf_cd,
            ROWS, 3 * INNER_, DIM_);
        attn_mfma_kernel<<<dim3(B_, H_), 256, 0, stream>>>(buf_cd, scale + i * H_, buf_hb);
        mgemm_kernel<1, float><<<dim3(DIM_ / 64, GY), 256, 0, stream>>>(
            buf_hb, out_w + (size_t)i * DIM_ * INNER_, out_b + i * DIM_, buf_x, buf_x,
            ROWS, DIM_, INNER_);
        ln_kernel<<<ROWS / 4, 256, 0, stream>>>(buf_x, DIM_, ln2_g + i * DIM_,
                                                ln2_b + i * DIM_, buf_hb, ROWS);
        int base = 0;
        for (int c = 0; c < 2; c++) {
            int mrows = (c == 0) ? 6336 : 6272;
            int gy = (mrows + 127) / 128;
            mgemm_kernel<2, bf16><<<dim3(MLP_ / 64, gy), 256, 0, stream>>>(
                buf_hb + (size_t)base * DIM_, ff_w1 + (size_t)i * MLP_ * DIM_,
                ff_b1 + i * MLP_, nullptr, buf_cd, mrows, MLP_, DIM_);
            mgemm_kernel<1, float><<<dim3(DIM_ / 64, gy), 256, 0, stream>>>(
                buf_cd, ff_w2 + (size_t)i * DIM_ * MLP_, ff_b2 + i * DIM_,
                buf_x + (size_t)base * DIM_, buf_x + (size_t)base * DIM_, mrows, DIM_, MLP_);
            base += mrows;
        }
    }

    ln_kernel<<<B_ / 4, 256, 0, stream>>>(buf_x, (long)N_ * DIM_, lnf_g, lnf_b, buf_cls, B_);
    head_kernel<<<250, 256, 0, stream>>>(buf_cls, head_w, head_b, (float*)d_out);
    diag_kernel<<<250, 256, 0, stream>>>(buf_x, (float*)d_out, 0, 1);
}